// Round 2
// baseline (771.981 us; speedup 1.0000x reference)
//
#include <hip/hip_runtime.h>
#include <math.h>

#define N_NODES 50000
#define N_EDGES 800000
#define N_GRAPHS 64
#define NREP 32
#define LN_EPS 1e-5f

// ---------------- cross-lane reductions ----------------
__device__ __forceinline__ float red32(float p) {
  p += __shfl_xor(p, 1);  p += __shfl_xor(p, 2);  p += __shfl_xor(p, 4);
  p += __shfl_xor(p, 8);  p += __shfl_xor(p, 16);
  return p;
}
__device__ __forceinline__ float red64(float p) {
  p += __shfl_xor(p, 1);  p += __shfl_xor(p, 2);  p += __shfl_xor(p, 4);
  p += __shfl_xor(p, 8);  p += __shfl_xor(p, 16); p += __shfl_xor(p, 32);
  return p;
}
// two independent head-group (16-lane) reduces, interleaved for ILP
__device__ __forceinline__ void red16x2(float& a, float& b) {
  float a1 = __shfl_xor(a, 1), b1 = __shfl_xor(b, 1); a += a1; b += b1;
  float a2 = __shfl_xor(a, 2), b2 = __shfl_xor(b, 2); a += a2; b += b2;
  float a4 = __shfl_xor(a, 4), b4 = __shfl_xor(b, 4); a += a4; b += b4;
  float a8 = __shfl_xor(a, 8), b8 = __shfl_xor(b, 8); a += a8; b += b8;
}

__device__ __forceinline__ unsigned f2bf(float f) {  // rne f32->bf16
  unsigned u = __float_as_uint(f);
  return (u + 0x7fffu + ((u >> 16) & 1u)) >> 16;
}

// ---------------- K0: xl1 = x @ Wl1, stored bf16-packed ----------------
__global__ __launch_bounds__(256) void k_xl1(const float* __restrict__ x,
                                             const float* __restrict__ Wl,
                                             unsigned* __restrict__ xlb) {
  int lane = threadIdx.x & 63;
  int n = blockIdx.x * 4 + (threadIdx.x >> 6);
  int c0 = lane * 4;
  float xn[8];
  {
    float4 a = *(const float4*)(x + n * 8);
    float4 b = *(const float4*)(x + n * 8 + 4);
    xn[0]=a.x; xn[1]=a.y; xn[2]=a.z; xn[3]=a.w;
    xn[4]=b.x; xn[5]=b.y; xn[6]=b.z; xn[7]=b.w;
  }
  float a0=0.f,a1=0.f,a2=0.f,a3=0.f;
#pragma unroll
  for (int k = 0; k < 8; ++k) {
    float4 w = *(const float4*)(Wl + k * 256 + c0);
    a0 += xn[k]*w.x; a1 += xn[k]*w.y; a2 += xn[k]*w.z; a3 += xn[k]*w.w;
  }
  unsigned lo = f2bf(a0) | (f2bf(a1) << 16);
  unsigned hi = f2bf(a2) | (f2bf(a3) << 16);
  *(uint2*)(xlb + (size_t)n * 128 + lane * 2) = make_uint2(lo, hi);
}

// ---------------- K1: per-dst degree + edge_attr sum ----------------
__global__ void k_hist(const int* __restrict__ dst, const float* __restrict__ ea,
                       int* __restrict__ deg, float* __restrict__ easum) {
  int e = blockIdx.x * 256 + threadIdx.x;
  if (e >= N_EDGES) return;
  int d = dst[e];
  atomicAdd(&deg[d], 1);
  atomicAdd(&easum[d], ea[e]);
}

// ---------------- K2: exclusive scan of padded lengths ----------------
// segment length = (deg+1 [self]) padded up to even; off2[n] = start
__global__ void k_scan(const int* __restrict__ deg, int* __restrict__ off2) {
  __shared__ int part[1024];
  int t = threadIdx.x;
  const int CH = (N_NODES + 1023) / 1024;  // 49
  int lo = t * CH, hi = min(lo + CH, N_NODES);
  int s = 0;
  for (int i = lo; i < hi; ++i) s += (deg[i] + 2) & ~1;   // padded len
  part[t] = s;
  __syncthreads();
  for (int off = 1; off < 1024; off <<= 1) {
    int v = (t >= off) ? part[t - off] : 0;
    __syncthreads();
    part[t] += v;
    __syncthreads();
  }
  int run = (t == 0) ? 0 : part[t - 1];
  for (int i = lo; i < hi; ++i) { off2[i] = run; run += (deg[i] + 2) & ~1; }
  if (t == 1023) off2[N_NODES] = part[1023];
}

// ---------------- K3: write self-loop entry (+sentinel pad) ----------------
__global__ void k_self(const int* __restrict__ deg, const float* __restrict__ easum,
                       const int* __restrict__ off2,
                       int* __restrict__ ssrc, float* __restrict__ sea) {
  int n = blockIdx.x * 256 + threadIdx.x;
  if (n >= N_NODES) return;
  int b = off2[n], d = deg[n];
  ssrc[b + d] = n;
  sea[b + d]  = easum[n] / fmaxf((float)d, 1.0f);
  if ((d & 1) == 0) { ssrc[b + d + 1] = -1; sea[b + d + 1] = 0.f; }  // sentinel
}

// ---------------- K4: counting-sort scatter (edges grouped by dst) ----------------
__global__ void k_scatter(const int* __restrict__ src, const int* __restrict__ dst,
                          const float* __restrict__ ea, const int* __restrict__ off2,
                          int* __restrict__ cursor, int* __restrict__ ssrc,
                          float* __restrict__ sea) {
  int e = blockIdx.x * 256 + threadIdx.x;
  if (e >= N_EDGES) return;
  int d = dst[e];
  int pos = off2[d] + atomicAdd(&cursor[d], 1);
  ssrc[pos] = src[e];
  sea[pos]  = ea[e];
}

// ---------------- K5: fused GATv2 layer 1 + bias + LN + ELU ----------------
// one wave per node; lane owns 4 channels (c0=lane*4), head = lane/16.
// xl gathered (bf16) from precomputed xl1; 2 edges per iteration.
__global__ __launch_bounds__(256) void k_gat1(
    const unsigned* __restrict__ xl1, const float* __restrict__ x,
    const float* __restrict__ Wr, const float* __restrict__ We,
    const float* __restrict__ att,
    const float* __restrict__ b1, const float* __restrict__ g1,
    const float* __restrict__ be1,
    const int* __restrict__ off2, const int* __restrict__ ssrc,
    const float* __restrict__ sea, float* __restrict__ h1) {
  int lane = threadIdx.x & 63;
  int n = blockIdx.x * 4 + (threadIdx.x >> 6);
  int c0 = lane * 4;

  float4 wev = *(const float4*)(We + c0);
  float4 atv = *(const float4*)(att + c0);

  float xn[8];
  {
    float4 a = *(const float4*)(x + n * 8);
    float4 b = *(const float4*)(x + n * 8 + 4);
    xn[0]=a.x; xn[1]=a.y; xn[2]=a.z; xn[3]=a.w;
    xn[4]=b.x; xn[5]=b.y; xn[6]=b.z; xn[7]=b.w;
  }
  float xr0=0.f, xr1=0.f, xr2=0.f, xr3=0.f;
#pragma unroll
  for (int k = 0; k < 8; ++k) {
    float4 w = *(const float4*)(Wr + k * 256 + c0);
    xr0 += xn[k]*w.x; xr1 += xn[k]*w.y; xr2 += xn[k]*w.z; xr3 += xn[k]*w.w;
  }

  int beg = off2[n];
  int pairs = (off2[n + 1] - beg) >> 1;   // >= 1 always (self-loop + pad)

  float den = 0.f, ac0=0.f, ac1=0.f, ac2=0.f, ac3=0.f;

  // prefetch pair 0
  int sA = ssrc[beg], sB = ssrc[beg + 1];
  float eA = sea[beg], eB = sea[beg + 1];
  uint2 uA = *(const uint2*)(xl1 + (size_t)max(sA, 0) * 128 + lane * 2);
  uint2 uB = *(const uint2*)(xl1 + (size_t)max(sB, 0) * 128 + lane * 2);

  for (int p = 0; p < pairs; ++p) {
    int   csB = sB;
    float ceA = eA, ceB = eB;
    uint2 cuA = uA, cuB = uB;
    if (p + 1 < pairs) {
      int j = beg + 2 * (p + 1);
      sA = ssrc[j]; sB = ssrc[j + 1];
      eA = sea[j];  eB = sea[j + 1];
      uA = *(const uint2*)(xl1 + (size_t)max(sA, 0) * 128 + lane * 2);
      uB = *(const uint2*)(xl1 + (size_t)max(sB, 0) * 128 + lane * 2);
    }
    // unpack bf16 -> f32
    float vA0 = __uint_as_float(cuA.x << 16), vA1 = __uint_as_float(cuA.x & 0xffff0000u);
    float vA2 = __uint_as_float(cuA.y << 16), vA3 = __uint_as_float(cuA.y & 0xffff0000u);
    float vB0 = __uint_as_float(cuB.x << 16), vB1 = __uint_as_float(cuB.x & 0xffff0000u);
    float vB2 = __uint_as_float(cuB.y << 16), vB3 = __uint_as_float(cuB.y & 0xffff0000u);

    float mA0 = vA0 + xr0 + ceA*wev.x; mA0 = mA0 > 0.f ? mA0 : 0.2f*mA0;
    float mA1 = vA1 + xr1 + ceA*wev.y; mA1 = mA1 > 0.f ? mA1 : 0.2f*mA1;
    float mA2 = vA2 + xr2 + ceA*wev.z; mA2 = mA2 > 0.f ? mA2 : 0.2f*mA2;
    float mA3 = vA3 + xr3 + ceA*wev.w; mA3 = mA3 > 0.f ? mA3 : 0.2f*mA3;
    float mB0 = vB0 + xr0 + ceB*wev.x; mB0 = mB0 > 0.f ? mB0 : 0.2f*mB0;
    float mB1 = vB1 + xr1 + ceB*wev.y; mB1 = mB1 > 0.f ? mB1 : 0.2f*mB1;
    float mB2 = vB2 + xr2 + ceB*wev.z; mB2 = mB2 > 0.f ? mB2 : 0.2f*mB2;
    float mB3 = vB3 + xr3 + ceB*wev.w; mB3 = mB3 > 0.f ? mB3 : 0.2f*mB3;

    float pA = mA0*atv.x + mA1*atv.y + mA2*atv.z + mA3*atv.w;
    float pB = mB0*atv.x + mB1*atv.y + mB2*atv.z + mB3*atv.w;
    red16x2(pA, pB);                       // per-head (16-lane) dot reduce

    float wA = __expf(pA);                 // no-max softmax: |p| small by scale
    float wB = (csB >= 0) ? __expf(pB) : 0.f;   // sentinel only in B slot
    den += wA + wB;
    ac0 = fmaf(wA, vA0, fmaf(wB, vB0, ac0));
    ac1 = fmaf(wA, vA1, fmaf(wB, vB1, ac1));
    ac2 = fmaf(wA, vA2, fmaf(wB, vB2, ac2));
    ac3 = fmaf(wA, vA3, fmaf(wB, vB3, ac3));
  }

  float inv = 1.0f / (den + 1e-16f);
  float4 bv = *(const float4*)(b1 + c0);
  float o0 = ac0*inv + bv.x, o1 = ac1*inv + bv.y;
  float o2 = ac2*inv + bv.z, o3 = ac3*inv + bv.w;
  float mu = red64(o0 + o1 + o2 + o3) * (1.0f / 256.0f);
  float d0 = o0-mu, d1 = o1-mu, d2 = o2-mu, d3 = o3-mu;
  float rstd = rsqrtf(red64(d0*d0 + d1*d1 + d2*d2 + d3*d3) * (1.0f/256.0f) + LN_EPS);
  float4 gv  = *(const float4*)(g1 + c0);
  float4 bev = *(const float4*)(be1 + c0);
  float y0 = d0*rstd*gv.x + bev.x; y0 = y0 > 0.f ? y0 : __expf(y0) - 1.0f;
  float y1 = d1*rstd*gv.y + bev.y; y1 = y1 > 0.f ? y1 : __expf(y1) - 1.0f;
  float y2 = d2*rstd*gv.z + bev.z; y2 = y2 > 0.f ? y2 : __expf(y2) - 1.0f;
  float y3 = d3*rstd*gv.w + bev.w; y3 = y3 > 0.f ? y3 : __expf(y3) - 1.0f;
  float4 o; o.x=y0; o.y=y1; o.z=y2; o.w=y3;
  *(float4*)(h1 + (size_t)n * 256 + c0) = o;
}

// ---------------- K6: xl2 = h1@Wl2, xr2 = h1@Wr2 (tiled f32 GEMM) ----------------
__global__ __launch_bounds__(256) void k_gemm2(
    const float* __restrict__ h1, const float* __restrict__ Wl2,
    const float* __restrict__ Wr2, float* __restrict__ xl2, float* __restrict__ xr2) {
  __shared__ float As[32][64];
  __shared__ float Bs[32][128];
  const float* B = blockIdx.y ? Wr2 : Wl2;
  float* C = blockIdx.y ? xr2 : xl2;
  int t = threadIdx.x;
  int bm0 = blockIdx.x * 64;
  int cg = t & 15, ng = t >> 4;
  int cc0 = cg * 8, m0 = ng * 4;
  float acc[4][8];
#pragma unroll
  for (int i = 0; i < 4; ++i)
#pragma unroll
    for (int j = 0; j < 8; ++j) acc[i][j] = 0.f;

  int lm = t & 63;
  int ks = (t >> 6) * 8;
  int brow = t >> 3;
  int bcol = (t & 7) * 16;

  for (int kc = 0; kc < 256; kc += 32) {
    int gm = bm0 + lm;
    float4 va, vb;
    if (gm < N_NODES) {
      va = *(const float4*)(h1 + (size_t)gm * 256 + kc + ks);
      vb = *(const float4*)(h1 + (size_t)gm * 256 + kc + ks + 4);
    } else { va = make_float4(0,0,0,0); vb = make_float4(0,0,0,0); }
    As[ks+0][lm]=va.x; As[ks+1][lm]=va.y; As[ks+2][lm]=va.z; As[ks+3][lm]=va.w;
    As[ks+4][lm]=vb.x; As[ks+5][lm]=vb.y; As[ks+6][lm]=vb.z; As[ks+7][lm]=vb.w;
#pragma unroll
    for (int j = 0; j < 4; ++j)
      *(float4*)(&Bs[brow][bcol + j*4]) =
        *(const float4*)(B + (size_t)(kc + brow) * 128 + bcol + j*4);
    __syncthreads();
#pragma unroll
    for (int k = 0; k < 32; ++k) {
      float4 a = *(const float4*)(&As[k][m0]);
      float4 pv = *(const float4*)(&Bs[k][cc0]);
      float4 qv = *(const float4*)(&Bs[k][cc0 + 4]);
      float av[4] = {a.x, a.y, a.z, a.w};
      float bv[8] = {pv.x, pv.y, pv.z, pv.w, qv.x, qv.y, qv.z, qv.w};
#pragma unroll
      for (int i = 0; i < 4; ++i)
#pragma unroll
        for (int j = 0; j < 8; ++j) acc[i][j] += av[i] * bv[j];
    }
    __syncthreads();
  }
#pragma unroll
  for (int i = 0; i < 4; ++i) {
    int gm = bm0 + m0 + i;
    if (gm < N_NODES) {
      float4 o0 = make_float4(acc[i][0], acc[i][1], acc[i][2], acc[i][3]);
      float4 o1 = make_float4(acc[i][4], acc[i][5], acc[i][6], acc[i][7]);
      *(float4*)(C + (size_t)gm * 128 + cc0)     = o0;
      *(float4*)(C + (size_t)gm * 128 + cc0 + 4) = o1;
    }
  }
}

// ---------------- K7: fused GATv2 layer 2 + bias + LN + ELU + pooled atomics ------
// one wave per node; 32 lanes per edge (4 ch/lane), 2 edges per iteration.
__global__ __launch_bounds__(256) void k_gat2(
    const float* __restrict__ xl2, const float* __restrict__ xr2,
    const float* __restrict__ We, const float* __restrict__ att,
    const float* __restrict__ b2, const float* __restrict__ g2,
    const float* __restrict__ be2,
    const int* __restrict__ off2, const int* __restrict__ ssrc,
    const float* __restrict__ sea,
    const int* __restrict__ batch,
    float* __restrict__ pool, float* __restrict__ cnt) {
  int lane = threadIdx.x & 63;
  int half = lane >> 5;           // which edge of the pair this lane serves
  int l32 = lane & 31;
  int n = blockIdx.x * 4 + (threadIdx.x >> 6);
  int c0 = l32 * 4;

  float4 wev = *(const float4*)(We + c0);
  float4 atv = *(const float4*)(att + c0);
  float4 xr  = *(const float4*)(xr2 + (size_t)n * 128 + c0);

  int beg = off2[n];
  int pairs = (off2[n + 1] - beg) >> 1;

  float den = 0.f, a0=0.f, a1=0.f, a2=0.f, a3=0.f;

  // prefetch pair 0, slot `half`
  int s = ssrc[beg + half];
  float ev = sea[beg + half];
  float4 v = *(const float4*)(xl2 + (size_t)max(s, 0) * 128 + c0);

  for (int p = 0; p < pairs; ++p) {
    int cs = s; float cev = ev; float4 cv = v;
    if (p + 1 < pairs) {
      int j = beg + 2 * (p + 1) + half;
      s = ssrc[j]; ev = sea[j];
      v = *(const float4*)(xl2 + (size_t)max(s, 0) * 128 + c0);
    }
    float m0 = cv.x + xr.x + cev*wev.x; m0 = m0 > 0.f ? m0 : 0.2f*m0;
    float m1 = cv.y + xr.y + cev*wev.y; m1 = m1 > 0.f ? m1 : 0.2f*m1;
    float m2 = cv.z + xr.z + cev*wev.z; m2 = m2 > 0.f ? m2 : 0.2f*m2;
    float m3 = cv.w + xr.w + cev*wev.w; m3 = m3 > 0.f ? m3 : 0.2f*m3;
    float pp = m0*atv.x + m1*atv.y + m2*atv.z + m3*atv.w;
    pp = red32(pp);                         // per-edge dot over this half
    float w = (cs >= 0) ? __expf(pp) : 0.f; // sentinel -> weight 0
    den += w;
    a0 = fmaf(w, cv.x, a0); a1 = fmaf(w, cv.y, a1);
    a2 = fmaf(w, cv.z, a2); a3 = fmaf(w, cv.w, a3);
  }
  // combine the two half-wave partials (both halves end with identical totals)
  den += __shfl_xor(den, 32);
  a0 += __shfl_xor(a0, 32); a1 += __shfl_xor(a1, 32);
  a2 += __shfl_xor(a2, 32); a3 += __shfl_xor(a3, 32);

  float inv = 1.0f / (den + 1e-16f);
  float4 bv = *(const float4*)(b2 + c0);
  float o0 = a0*inv + bv.x, o1 = a1*inv + bv.y;
  float o2 = a2*inv + bv.z, o3 = a3*inv + bv.w;
  // LN over 128 channels; values duplicated across halves -> divide by 256
  float mu = red64(o0 + o1 + o2 + o3) * (1.0f / 256.0f);
  float d0 = o0-mu, d1 = o1-mu, d2 = o2-mu, d3 = o3-mu;
  float rstd = rsqrtf(red64(d0*d0 + d1*d1 + d2*d2 + d3*d3) * (1.0f/256.0f) + LN_EPS);
  float4 gv  = *(const float4*)(g2 + c0);
  float4 bev = *(const float4*)(be2 + c0);
  float y0 = d0*rstd*gv.x + bev.x; y0 = y0 > 0.f ? y0 : __expf(y0) - 1.0f;
  float y1 = d1*rstd*gv.y + bev.y; y1 = y1 > 0.f ? y1 : __expf(y1) - 1.0f;
  float y2 = d2*rstd*gv.z + bev.z; y2 = y2 > 0.f ? y2 : __expf(y2) - 1.0f;
  float y3 = d3*rstd*gv.w + bev.w; y3 = y3 > 0.f ? y3 : __expf(y3) - 1.0f;

  if (half == 0) {
    int g = batch[n];
    int r = blockIdx.x & (NREP - 1);
    float* pp2 = pool + ((size_t)(r * N_GRAPHS + g)) * 128 + c0;
    atomicAdd(pp2 + 0, y0); atomicAdd(pp2 + 1, y1);
    atomicAdd(pp2 + 2, y2); atomicAdd(pp2 + 3, y3);
    if (l32 == 0) atomicAdd(&cnt[r * N_GRAPHS + g], 1.0f);
  }
}

// ---------------- K8: reduce replicas, divide by count ----------------
__global__ void k_final(const float* __restrict__ pool, const float* __restrict__ cnt,
                        float* __restrict__ out) {
  int idx = blockIdx.x * 256 + threadIdx.x;
  if (idx >= N_GRAPHS * 128) return;
  int g = idx >> 7, c = idx & 127;
  float s = 0.f, nn = 0.f;
#pragma unroll
  for (int r = 0; r < NREP; ++r) {
    s  += pool[((size_t)(r * N_GRAPHS + g)) * 128 + c];
    nn += cnt[r * N_GRAPHS + g];
  }
  out[idx] = s / fmaxf(nn, 1.0f);
}

// ---------------- launch ----------------
extern "C" void kernel_launch(void* const* d_in, const int* in_sizes, int n_in,
                              void* d_out, int out_size, void* d_ws, size_t ws_size,
                              hipStream_t stream) {
  const float* x    = (const float*)d_in[0];
  const int*   ei   = (const int*)  d_in[1];
  const float* ea   = (const float*)d_in[2];
  const int*   batch= (const int*)  d_in[3];
  const float* Wl1  = (const float*)d_in[4];
  const float* Wr1  = (const float*)d_in[5];
  const float* We1  = (const float*)d_in[6];
  const float* att1 = (const float*)d_in[7];
  const float* b1   = (const float*)d_in[8];
  const float* g1   = (const float*)d_in[9];
  const float* be1  = (const float*)d_in[10];
  const float* Wl2  = (const float*)d_in[11];
  const float* Wr2  = (const float*)d_in[12];
  const float* We2  = (const float*)d_in[13];
  const float* att2 = (const float*)d_in[14];
  const float* b2   = (const float*)d_in[15];
  const float* g2   = (const float*)d_in[16];
  const float* be2  = (const float*)d_in[17];
  const int* srcp = ei;
  const int* dstp = ei + N_EDGES;

  const int MAXE2 = N_EDGES + 2 * N_NODES;   // padded CSR capacity

  char* ws = (char*)d_ws;
  size_t off = 0;
  auto alloc = [&](size_t bytes) {
    char* p = ws + off; off += (bytes + 15) & ~(size_t)15; return p;
  };
  int*      deg   = (int*)     alloc((size_t)N_NODES * 4);
  float*    easum = (float*)   alloc((size_t)N_NODES * 4);
  int*      cursor= (int*)     alloc((size_t)N_NODES * 4);
  int*      off2  = (int*)     alloc((size_t)(N_NODES + 1) * 4);
  int*      ssrc  = (int*)     alloc((size_t)MAXE2 * 4);
  float*    sea   = (float*)   alloc((size_t)MAXE2 * 4);
  unsigned* xl1b  = (unsigned*)alloc((size_t)N_NODES * 128 * 4);  // bf16-packed 256ch
  float*    h1    = (float*)   alloc((size_t)N_NODES * 256 * 4);
  float*    xl2   = (float*)   alloc((size_t)N_NODES * 128 * 4);
  float*    xr2   = (float*)   alloc((size_t)N_NODES * 128 * 4);
  float*    pool  = (float*)   alloc((size_t)NREP * N_GRAPHS * 128 * 4);
  float*    cnt   = (float*)   alloc((size_t)NREP * N_GRAPHS * 4);

  hipMemsetAsync(deg, 0, (char*)off2 - (char*)deg, stream);           // deg,easum,cursor
  hipMemsetAsync(pool, 0, ((char*)cnt + (((size_t)NREP*N_GRAPHS*4 + 15) & ~(size_t)15))
                           - (char*)pool, stream);

  k_xl1    <<<N_NODES / 4, 256, 0, stream>>>(x, Wl1, xl1b);
  k_hist   <<<N_EDGES / 256, 256, 0, stream>>>(dstp, ea, deg, easum);
  k_scan   <<<1, 1024, 0, stream>>>(deg, off2);
  k_self   <<<(N_NODES + 255) / 256, 256, 0, stream>>>(deg, easum, off2, ssrc, sea);
  k_scatter<<<N_EDGES / 256, 256, 0, stream>>>(srcp, dstp, ea, off2, cursor, ssrc, sea);
  k_gat1   <<<N_NODES / 4, 256, 0, stream>>>(xl1b, x, Wr1, We1, att1, b1, g1, be1,
                                             off2, ssrc, sea, h1);
  dim3 g5((N_NODES + 63) / 64, 2);
  k_gemm2  <<<g5, 256, 0, stream>>>(h1, Wl2, Wr2, xl2, xr2);
  k_gat2   <<<N_NODES / 4, 256, 0, stream>>>(xl2, xr2, We2, att2, b2, g2, be2,
                                             off2, ssrc, sea, batch, pool, cnt);
  k_final  <<<(N_GRAPHS * 128) / 256, 256, 0, stream>>>(pool, cnt, (float*)d_out);
}

// Round 4
// 579.608 us; speedup vs baseline: 1.3319x; 1.3319x over previous
//
#include <hip/hip_runtime.h>
#include <math.h>

#define N_NODES 50000
#define N_EDGES 800000
#define N_GRAPHS 64
#define NREP 32
#define LN_EPS 1e-5f

typedef __attribute__((ext_vector_type(8))) short bf16x8;
typedef __attribute__((ext_vector_type(4))) float f32x4;

// ---------------- cross-lane reductions ----------------
__device__ __forceinline__ float red32(float p) {
  p += __shfl_xor(p, 1);  p += __shfl_xor(p, 2);  p += __shfl_xor(p, 4);
  p += __shfl_xor(p, 8);  p += __shfl_xor(p, 16);
  return p;
}
__device__ __forceinline__ float red64(float p) {
  p += __shfl_xor(p, 1);  p += __shfl_xor(p, 2);  p += __shfl_xor(p, 4);
  p += __shfl_xor(p, 8);  p += __shfl_xor(p, 16); p += __shfl_xor(p, 32);
  return p;
}
__device__ __forceinline__ void red16x2(float& a, float& b) {
  float a1 = __shfl_xor(a, 1), b1 = __shfl_xor(b, 1); a += a1; b += b1;
  float a2 = __shfl_xor(a, 2), b2 = __shfl_xor(b, 2); a += a2; b += b2;
  float a4 = __shfl_xor(a, 4), b4 = __shfl_xor(b, 4); a += a4; b += b4;
  float a8 = __shfl_xor(a, 8), b8 = __shfl_xor(b, 8); a += a8; b += b8;
}

__device__ __forceinline__ unsigned f2bf(float f) {  // rne f32->bf16
  unsigned u = __float_as_uint(f);
  return (u + 0x7fffu + ((u >> 16) & 1u)) >> 16;
}

// ---------------- K1: per-dst degree + edge_attr sum ----------------
__global__ void k_hist(const int* __restrict__ dst, const float* __restrict__ ea,
                       int* __restrict__ deg, float* __restrict__ easum) {
  int e = blockIdx.x * 256 + threadIdx.x;
  if (e >= N_EDGES) return;
  int d = dst[e];
  atomicAdd(&deg[d], 1);
  atomicAdd(&easum[d], ea[e]);
}

// ---------------- K2: exclusive scan of padded lengths ----------------
__global__ void k_scan(const int* __restrict__ deg, int* __restrict__ off2) {
  __shared__ int part[1024];
  int t = threadIdx.x;
  const int CH = (N_NODES + 1023) / 1024;  // 49
  int lo = t * CH, hi = min(lo + CH, N_NODES);
  int s = 0;
  for (int i = lo; i < hi; ++i) s += (deg[i] + 2) & ~1;   // +self, pad to even
  part[t] = s;
  __syncthreads();
  for (int off = 1; off < 1024; off <<= 1) {
    int v = (t >= off) ? part[t - off] : 0;
    __syncthreads();
    part[t] += v;
    __syncthreads();
  }
  int run = (t == 0) ? 0 : part[t - 1];
  for (int i = lo; i < hi; ++i) { off2[i] = run; run += (deg[i] + 2) & ~1; }
  if (t == 1023) off2[N_NODES] = part[1023];
}

// ---------------- K3: write self-loop entry (+sentinel pad) ----------------
__global__ void k_self(const int* __restrict__ deg, const float* __restrict__ easum,
                       const int* __restrict__ off2,
                       int* __restrict__ ssrc, float* __restrict__ sea) {
  int n = blockIdx.x * 256 + threadIdx.x;
  if (n >= N_NODES) return;
  int b = off2[n], d = deg[n];
  ssrc[b + d] = n;
  sea[b + d]  = easum[n] / fmaxf((float)d, 1.0f);
  if ((d & 1) == 0) { ssrc[b + d + 1] = -1; sea[b + d + 1] = 0.f; }  // sentinel
}

// ---------------- K4: counting-sort scatter (edges grouped by dst) ----------------
__global__ void k_scatter(const int* __restrict__ src, const int* __restrict__ dst,
                          const float* __restrict__ ea, const int* __restrict__ off2,
                          int* __restrict__ cursor, int* __restrict__ ssrc,
                          float* __restrict__ sea) {
  int e = blockIdx.x * 256 + threadIdx.x;
  if (e >= N_EDGES) return;
  int d = dst[e];
  int pos = off2[d] + atomicAdd(&cursor[d], 1);
  ssrc[pos] = src[e];
  sea[pos]  = ea[e];
}

// ---------------- K5: transpose+cast weights [Wl2|Wr2] -> Btp[256][256] bf16 ------
__global__ void k_wprep(const float* __restrict__ Wl2, const float* __restrict__ Wr2,
                        unsigned short* __restrict__ Btp) {
  int nIdx = blockIdx.x;           // output col 0..255
  int k = threadIdx.x;             // 0..255
  float v = (nIdx < 128) ? Wl2[k * 128 + nIdx] : Wr2[k * 128 + (nIdx - 128)];
  Btp[nIdx * 256 + k] = (unsigned short)f2bf(v);
}

// ---------------- K6: fused GATv2 layer 1 + bias + LN + ELU -> h1 (bf16) ----------
// one wave per node; lane owns 4 channels (c0=lane*4), head = lane/16.
// xl[src] recomputed on the fly from x[src] (1.6MB, L2-resident) -- VALU-bound.
__global__ __launch_bounds__(256) void k_gat1(
    const float* __restrict__ x,
    const float* __restrict__ Wl, const float* __restrict__ Wr,
    const float* __restrict__ We, const float* __restrict__ att,
    const float* __restrict__ b1, const float* __restrict__ g1,
    const float* __restrict__ be1,
    const int* __restrict__ off2, const int* __restrict__ ssrc,
    const float* __restrict__ sea, unsigned* __restrict__ h1b) {
  int lane = threadIdx.x & 63;
  int n = blockIdx.x * 4 + (threadIdx.x >> 6);
  int c0 = lane * 4;

  float4 wev = *(const float4*)(We + c0);
  float4 atv = *(const float4*)(att + c0);

  float xn[8];
  {
    float4 a = *(const float4*)(x + n * 8);
    float4 b = *(const float4*)(x + n * 8 + 4);
    xn[0]=a.x; xn[1]=a.y; xn[2]=a.z; xn[3]=a.w;
    xn[4]=b.x; xn[5]=b.y; xn[6]=b.z; xn[7]=b.w;
  }
  float xr0=0.f, xr1=0.f, xr2=0.f, xr3=0.f;
  float wl[8][4];
#pragma unroll
  for (int k = 0; k < 8; ++k) {
    float4 wr = *(const float4*)(Wr + k * 256 + c0);
    xr0 += xn[k]*wr.x; xr1 += xn[k]*wr.y; xr2 += xn[k]*wr.z; xr3 += xn[k]*wr.w;
    float4 w = *(const float4*)(Wl + k * 256 + c0);
    wl[k][0]=w.x; wl[k][1]=w.y; wl[k][2]=w.z; wl[k][3]=w.w;
  }

  int beg = off2[n];
  int pairs = (off2[n + 1] - beg) >> 1;   // >= 1 (self-loop + pad)

  float den = 0.f, ac0=0.f, ac1=0.f, ac2=0.f, ac3=0.f;

  // prefetch pair 0
  int sA = ssrc[beg], sB = ssrc[beg + 1];
  float eA = sea[beg], eB = sea[beg + 1];
  float4 xaA = *(const float4*)(x + max(sA,0) * 8);
  float4 xbA = *(const float4*)(x + max(sA,0) * 8 + 4);
  float4 xaB = *(const float4*)(x + max(sB,0) * 8);
  float4 xbB = *(const float4*)(x + max(sB,0) * 8 + 4);

  for (int p = 0; p < pairs; ++p) {
    int   csB = sB;
    float ceA = eA, ceB = eB;
    float xsA[8] = {xaA.x,xaA.y,xaA.z,xaA.w,xbA.x,xbA.y,xbA.z,xbA.w};
    float xsB[8] = {xaB.x,xaB.y,xaB.z,xaB.w,xbB.x,xbB.y,xbB.z,xbB.w};
    if (p + 1 < pairs) {
      int j = beg + 2 * (p + 1);
      sA = ssrc[j]; sB = ssrc[j + 1];
      eA = sea[j];  eB = sea[j + 1];
      xaA = *(const float4*)(x + max(sA,0) * 8);
      xbA = *(const float4*)(x + max(sA,0) * 8 + 4);
      xaB = *(const float4*)(x + max(sB,0) * 8);
      xbB = *(const float4*)(x + max(sB,0) * 8 + 4);
    }
    // xl on the fly (32 FMA per edge per lane)
    float vA0=0.f,vA1=0.f,vA2=0.f,vA3=0.f, vB0=0.f,vB1=0.f,vB2=0.f,vB3=0.f;
#pragma unroll
    for (int k = 0; k < 8; ++k) {
      vA0 = fmaf(xsA[k], wl[k][0], vA0); vA1 = fmaf(xsA[k], wl[k][1], vA1);
      vA2 = fmaf(xsA[k], wl[k][2], vA2); vA3 = fmaf(xsA[k], wl[k][3], vA3);
      vB0 = fmaf(xsB[k], wl[k][0], vB0); vB1 = fmaf(xsB[k], wl[k][1], vB1);
      vB2 = fmaf(xsB[k], wl[k][2], vB2); vB3 = fmaf(xsB[k], wl[k][3], vB3);
    }
    float mA0 = vA0 + xr0 + ceA*wev.x; mA0 = mA0 > 0.f ? mA0 : 0.2f*mA0;
    float mA1 = vA1 + xr1 + ceA*wev.y; mA1 = mA1 > 0.f ? mA1 : 0.2f*mA1;
    float mA2 = vA2 + xr2 + ceA*wev.z; mA2 = mA2 > 0.f ? mA2 : 0.2f*mA2;
    float mA3 = vA3 + xr3 + ceA*wev.w; mA3 = mA3 > 0.f ? mA3 : 0.2f*mA3;
    float mB0 = vB0 + xr0 + ceB*wev.x; mB0 = mB0 > 0.f ? mB0 : 0.2f*mB0;
    float mB1 = vB1 + xr1 + ceB*wev.y; mB1 = mB1 > 0.f ? mB1 : 0.2f*mB1;
    float mB2 = vB2 + xr2 + ceB*wev.z; mB2 = mB2 > 0.f ? mB2 : 0.2f*mB2;
    float mB3 = vB3 + xr3 + ceB*wev.w; mB3 = mB3 > 0.f ? mB3 : 0.2f*mB3;

    float pA = mA0*atv.x + mA1*atv.y + mA2*atv.z + mA3*atv.w;
    float pB = mB0*atv.x + mB1*atv.y + mB2*atv.z + mB3*atv.w;
    red16x2(pA, pB);

    float wA = __expf(pA);                     // no-max softmax (logits small)
    float wB = (csB >= 0) ? __expf(pB) : 0.f;  // sentinel only in B slot
    den += wA + wB;
    ac0 = fmaf(wA, vA0, fmaf(wB, vB0, ac0));
    ac1 = fmaf(wA, vA1, fmaf(wB, vB1, ac1));
    ac2 = fmaf(wA, vA2, fmaf(wB, vB2, ac2));
    ac3 = fmaf(wA, vA3, fmaf(wB, vB3, ac3));
  }

  float inv = 1.0f / (den + 1e-16f);
  float4 bv = *(const float4*)(b1 + c0);
  float o0 = ac0*inv + bv.x, o1 = ac1*inv + bv.y;
  float o2 = ac2*inv + bv.z, o3 = ac3*inv + bv.w;
  float mu = red64(o0 + o1 + o2 + o3) * (1.0f / 256.0f);
  float d0 = o0-mu, d1 = o1-mu, d2 = o2-mu, d3 = o3-mu;
  float rstd = rsqrtf(red64(d0*d0 + d1*d1 + d2*d2 + d3*d3) * (1.0f/256.0f) + LN_EPS);
  float4 gv  = *(const float4*)(g1 + c0);
  float4 bev = *(const float4*)(be1 + c0);
  float y0 = d0*rstd*gv.x + bev.x; y0 = y0 > 0.f ? y0 : __expf(y0) - 1.0f;
  float y1 = d1*rstd*gv.y + bev.y; y1 = y1 > 0.f ? y1 : __expf(y1) - 1.0f;
  float y2 = d2*rstd*gv.z + bev.z; y2 = y2 > 0.f ? y2 : __expf(y2) - 1.0f;
  float y3 = d3*rstd*gv.w + bev.w; y3 = y3 > 0.f ? y3 : __expf(y3) - 1.0f;
  unsigned lo = f2bf(y0) | (f2bf(y1) << 16);
  unsigned hi = f2bf(y2) | (f2bf(y3) << 16);
  *(uint2*)(h1b + (size_t)n * 128 + lane * 2) = make_uint2(lo, hi);
}

// ---------------- K7: MFMA GEMM  [xl2|xr2] = h1(bf16) @ Btp^T ----------------
// BM=64, BN=64 (blockIdx.y selects 64-col panel of 256), K=256 fully in LDS.
// 4 waves; wave w owns rows [16w,16w+16) x all 64 cols (4 16x16 tiles).
__global__ __launch_bounds__(256) void k_gemm2(
    const unsigned* __restrict__ h1b, const unsigned short* __restrict__ Btp,
    unsigned short* __restrict__ xl2b, float* __restrict__ xr2) {
  __shared__ unsigned short Ash[64][264];
  __shared__ unsigned short Bsh[64][264];
  int t = threadIdx.x;
  int bm0 = blockIdx.x * 64;
  int n0  = blockIdx.y * 64;

  // stage A (64 rows x 256 bf16) and B panel (64 cols x 256 bf16)
#pragma unroll
  for (int i = 0; i < 8; ++i) {
    int idx = t + 256 * i;          // uint4 index; 2048 total
    int row = idx >> 5, c4 = idx & 31;
    int gm = bm0 + row;
    uint4 va = (gm < N_NODES) ? *(const uint4*)(h1b + (size_t)gm * 128 + c4 * 4)
                              : make_uint4(0,0,0,0);
    *(uint4*)(&Ash[row][c4 * 8]) = va;
    uint4 vb = *(const uint4*)((const unsigned*)Btp + (size_t)(n0 + row) * 128 + c4 * 4);
    *(uint4*)(&Bsh[row][c4 * 8]) = vb;
  }
  __syncthreads();

  int lane = t & 63, w = t >> 6;
  int lm = lane & 15, lk = (lane >> 4) * 8;
  f32x4 acc[4];
#pragma unroll
  for (int i = 0; i < 4; ++i) acc[i] = (f32x4){0.f,0.f,0.f,0.f};

#pragma unroll
  for (int kk = 0; kk < 8; ++kk) {
    bf16x8 a = *(const bf16x8*)(&Ash[16*w + lm][kk*32 + lk]);
#pragma unroll
    for (int tt = 0; tt < 4; ++tt) {
      bf16x8 b = *(const bf16x8*)(&Bsh[16*tt + lm][kk*32 + lk]);
      acc[tt] = __builtin_amdgcn_mfma_f32_16x16x32_bf16(a, b, acc[tt], 0, 0, 0);
    }
  }

  // C layout: col = lane&15, row = (lane>>4)*4 + reg
#pragma unroll
  for (int tt = 0; tt < 4; ++tt) {
#pragma unroll
    for (int r = 0; r < 4; ++r) {
      int node = bm0 + 16*w + (lane >> 4) * 4 + r;
      if (node < N_NODES) {
        int colg = n0 + tt * 16 + lm;
        float v = acc[tt][r];
        if (colg < 128) xl2b[(size_t)node * 128 + colg] = (unsigned short)f2bf(v);
        else            xr2 [(size_t)node * 128 + (colg - 128)] = v;
      }
    }
  }
}

// ---------------- K8: fused GATv2 layer 2 + bias + LN + ELU + pooled atomics ------
// one wave per node; 32 lanes per edge (4 ch/lane), 2 edges/iter, depth-2 pipeline.
__global__ __launch_bounds__(256) void k_gat2(
    const unsigned* __restrict__ xl2b, const float* __restrict__ xr2,
    const float* __restrict__ We, const float* __restrict__ att,
    const float* __restrict__ b2, const float* __restrict__ g2,
    const float* __restrict__ be2,
    const int* __restrict__ off2, const int* __restrict__ ssrc,
    const float* __restrict__ sea,
    const int* __restrict__ batch,
    float* __restrict__ pool, float* __restrict__ cnt) {
  int tid = threadIdx.x;
  int lane = tid & 63, wid = tid >> 6;
  int half = lane >> 5, l32 = lane & 31;
  int n = blockIdx.x * 4 + wid;
  int c0 = l32 * 4;

  float4 wev = *(const float4*)(We + c0);
  float4 atv = *(const float4*)(att + c0);
  float4 xr  = *(const float4*)(xr2 + (size_t)n * 128 + c0);

  int beg = off2[n];
  int pairs = (off2[n + 1] - beg) >> 1;

  float den = 0.f, a0=0.f, a1=0.f, a2=0.f, a3=0.f;

  // 2-deep pipeline: each half-wave owns one edge per pair
  int s0 = ssrc[beg + half];
  float e0 = sea[beg + half];
  uint2 u0 = *(const uint2*)(xl2b + (size_t)max(s0,0) * 64 + l32 * 2);
  int s1 = -1; float e1 = 0.f; uint2 u1 = make_uint2(0,0);
  if (pairs > 1) {
    int j = beg + 2 + half;
    s1 = ssrc[j]; e1 = sea[j];
    u1 = *(const uint2*)(xl2b + (size_t)max(s1,0) * 64 + l32 * 2);
  }

  for (int p = 0; p < pairs; ++p) {
    int cs = s0; float ce = e0; uint2 cu = u0;
    s0 = s1; e0 = e1; u0 = u1;
    if (p + 2 < pairs) {
      int j = beg + 2 * (p + 2) + half;
      s1 = ssrc[j]; e1 = sea[j];
      u1 = *(const uint2*)(xl2b + (size_t)max(s1,0) * 64 + l32 * 2);
    }
    float v0 = __uint_as_float(cu.x << 16), v1 = __uint_as_float(cu.x & 0xffff0000u);
    float v2 = __uint_as_float(cu.y << 16), v3 = __uint_as_float(cu.y & 0xffff0000u);
    float m0 = v0 + xr.x + ce*wev.x; m0 = m0 > 0.f ? m0 : 0.2f*m0;
    float m1 = v1 + xr.y + ce*wev.y; m1 = m1 > 0.f ? m1 : 0.2f*m1;
    float m2 = v2 + xr.z + ce*wev.z; m2 = m2 > 0.f ? m2 : 0.2f*m2;
    float m3 = v3 + xr.w + ce*wev.w; m3 = m3 > 0.f ? m3 : 0.2f*m3;
    float pp = m0*atv.x + m1*atv.y + m2*atv.z + m3*atv.w;
    pp = red32(pp);
    float w = (cs >= 0) ? __expf(pp) : 0.f;
    den += w;
    a0 = fmaf(w, v0, a0); a1 = fmaf(w, v1, a1);
    a2 = fmaf(w, v2, a2); a3 = fmaf(w, v3, a3);
  }
  den += __shfl_xor(den, 32);
  a0 += __shfl_xor(a0, 32); a1 += __shfl_xor(a1, 32);
  a2 += __shfl_xor(a2, 32); a3 += __shfl_xor(a3, 32);

  float inv = 1.0f / (den + 1e-16f);
  float4 bv = *(const float4*)(b2 + c0);
  float o0 = a0*inv + bv.x, o1 = a1*inv + bv.y;
  float o2 = a2*inv + bv.z, o3 = a3*inv + bv.w;
  float mu = red64(o0 + o1 + o2 + o3) * (1.0f / 256.0f);   // each ch counted twice
  float d0 = o0-mu, d1 = o1-mu, d2 = o2-mu, d3 = o3-mu;
  float rstd = rsqrtf(red64(d0*d0 + d1*d1 + d2*d2 + d3*d3) * (1.0f/256.0f) + LN_EPS);
  float4 gv  = *(const float4*)(g2 + c0);
  float4 bev = *(const float4*)(be2 + c0);
  float y0 = d0*rstd*gv.x + bev.x; y0 = y0 > 0.f ? y0 : __expf(y0) - 1.0f;
  float y1 = d1*rstd*gv.y + bev.y; y1 = y1 > 0.f ? y1 : __expf(y1) - 1.0f;
  float y2 = d2*rstd*gv.z + bev.z; y2 = y2 > 0.f ? y2 : __expf(y2) - 1.0f;
  float y3 = d3*rstd*gv.w + bev.w; y3 = y3 > 0.f ? y3 : __expf(y3) - 1.0f;

  // block-level pool dedup (batch sorted -> usually 1 graph per block)
  __shared__ float pbuf[4][128];
  __shared__ int gbuf[4];
  if (half == 0) {
    pbuf[wid][c0+0] = y0; pbuf[wid][c0+1] = y1;
    pbuf[wid][c0+2] = y2; pbuf[wid][c0+3] = y3;
  }
  if (lane == 0) gbuf[wid] = batch[n];
  __syncthreads();
  if (wid == 0) {
    int r = blockIdx.x & (NREP - 1);
    int ch = lane;                       // handles ch and ch+64
    float acc0 = pbuf[0][ch], acc1 = pbuf[0][ch+64];
    int cg = gbuf[0], cn = 1;
#pragma unroll
    for (int i = 1; i < 4; ++i) {
      if (gbuf[i] == cg) { acc0 += pbuf[i][ch]; acc1 += pbuf[i][ch+64]; cn++; }
      else {
        float* pp = pool + ((size_t)(r * N_GRAPHS + cg)) * 128;
        atomicAdd(pp + ch, acc0); atomicAdd(pp + ch + 64, acc1);
        if (lane == 0) atomicAdd(&cnt[r * N_GRAPHS + cg], (float)cn);
        cg = gbuf[i]; acc0 = pbuf[i][ch]; acc1 = pbuf[i][ch+64]; cn = 1;
      }
    }
    float* pp = pool + ((size_t)(r * N_GRAPHS + cg)) * 128;
    atomicAdd(pp + ch, acc0); atomicAdd(pp + ch + 64, acc1);
    if (lane == 0) atomicAdd(&cnt[r * N_GRAPHS + cg], (float)cn);
  }
}

// ---------------- K9: reduce replicas, divide by count ----------------
__global__ void k_final(const float* __restrict__ pool, const float* __restrict__ cnt,
                        float* __restrict__ out) {
  int idx = blockIdx.x * 256 + threadIdx.x;
  if (idx >= N_GRAPHS * 128) return;
  int g = idx >> 7, c = idx & 127;
  float s = 0.f, nn = 0.f;
#pragma unroll
  for (int r = 0; r < NREP; ++r) {
    s  += pool[((size_t)(r * N_GRAPHS + g)) * 128 + c];
    nn += cnt[r * N_GRAPHS + g];
  }
  out[idx] = s / fmaxf(nn, 1.0f);
}

// ---------------- launch ----------------
extern "C" void kernel_launch(void* const* d_in, const int* in_sizes, int n_in,
                              void* d_out, int out_size, void* d_ws, size_t ws_size,
                              hipStream_t stream) {
  const float* x    = (const float*)d_in[0];
  const int*   ei   = (const int*)  d_in[1];
  const float* ea   = (const float*)d_in[2];
  const int*   batch= (const int*)  d_in[3];
  const float* Wl1  = (const float*)d_in[4];
  const float* Wr1  = (const float*)d_in[5];
  const float* We1  = (const float*)d_in[6];
  const float* att1 = (const float*)d_in[7];
  const float* b1   = (const float*)d_in[8];
  const float* g1   = (const float*)d_in[9];
  const float* be1  = (const float*)d_in[10];
  const float* Wl2  = (const float*)d_in[11];
  const float* Wr2  = (const float*)d_in[12];
  const float* We2  = (const float*)d_in[13];
  const float* att2 = (const float*)d_in[14];
  const float* b2   = (const float*)d_in[15];
  const float* g2   = (const float*)d_in[16];
  const float* be2  = (const float*)d_in[17];
  const int* srcp = ei;
  const int* dstp = ei + N_EDGES;

  const int MAXE2 = N_EDGES + 2 * N_NODES;

  char* ws = (char*)d_ws;
  size_t off = 0;
  auto alloc = [&](size_t bytes) {
    char* p = ws + off; off += (bytes + 15) & ~(size_t)15; return p;
  };
  int*            deg   = (int*)           alloc((size_t)N_NODES * 4);
  float*          easum = (float*)         alloc((size_t)N_NODES * 4);
  int*            cursor= (int*)           alloc((size_t)N_NODES * 4);
  int*            off2  = (int*)           alloc((size_t)(N_NODES + 1) * 4);
  int*            ssrc  = (int*)           alloc((size_t)MAXE2 * 4);
  float*          sea   = (float*)         alloc((size_t)MAXE2 * 4);
  unsigned*       h1b   = (unsigned*)      alloc((size_t)N_NODES * 128 * 4);  // bf16 256ch
  unsigned short* xl2b  = (unsigned short*)alloc((size_t)N_NODES * 128 * 2);  // bf16 128ch
  float*          xr2   = (float*)         alloc((size_t)N_NODES * 128 * 4);
  unsigned short* Btp   = (unsigned short*)alloc((size_t)256 * 256 * 2);
  float*          pool  = (float*)         alloc((size_t)NREP * N_GRAPHS * 128 * 4);
  float*          cnt   = (float*)         alloc((size_t)NREP * N_GRAPHS * 4);

  (void)hipMemsetAsync(deg, 0, (char*)off2 - (char*)deg, stream);   // deg, easum, cursor
  (void)hipMemsetAsync(pool, 0, ((char*)cnt + (((size_t)NREP*N_GRAPHS*4 + 15) & ~(size_t)15))
                           - (char*)pool, stream);

  k_hist   <<<N_EDGES / 256, 256, 0, stream>>>(dstp, ea, deg, easum);
  k_wprep  <<<256, 256, 0, stream>>>(Wl2, Wr2, Btp);
  k_scan   <<<1, 1024, 0, stream>>>(deg, off2);
  k_self   <<<(N_NODES + 255) / 256, 256, 0, stream>>>(deg, easum, off2, ssrc, sea);
  k_scatter<<<N_EDGES / 256, 256, 0, stream>>>(srcp, dstp, ea, off2, cursor, ssrc, sea);
  k_gat1   <<<N_NODES / 4, 256, 0, stream>>>(x, Wl1, Wr1, We1, att1, b1, g1, be1,
                                             off2, ssrc, sea, h1b);
  dim3 g7((N_NODES + 63) / 64, 4);
  k_gemm2  <<<g7, 256, 0, stream>>>(h1b, Btp, xl2b, xr2);
  k_gat2   <<<N_NODES / 4, 256, 0, stream>>>((const unsigned*)xl2b, xr2, We2, att2,
                                             b2, g2, be2,
                                             off2, ssrc, sea, batch, pool, cnt);
  k_final  <<<(N_GRAPHS * 128) / 256, 256, 0, stream>>>(pool, cnt, (float*)d_out);
}

// Round 6
// 540.327 us; speedup vs baseline: 1.4287x; 1.0727x over previous
//
#include <hip/hip_runtime.h>
#include <math.h>

#define N_NODES 50000
#define N_EDGES 800000
#define N_GRAPHS 64
#define NREP 32
#define LN_EPS 1e-5f

typedef __attribute__((ext_vector_type(8))) short bf16x8;
typedef __attribute__((ext_vector_type(4))) float f32x4;
typedef __attribute__((ext_vector_type(2))) _Float16 half2v;

// ---------------- DPP-based reductions (no LDS latency) ----------------
template <int CTRL>
__device__ __forceinline__ float dppadd(float v) {
  int t = __builtin_amdgcn_update_dpp(0, __float_as_int(v), CTRL, 0xF, 0xF, true);
  return v + __int_as_float(t);
}
// sum across each row of 16 lanes: quad xor1, quad xor2, half-mirror, mirror
__device__ __forceinline__ float red16d(float p) {
  p = dppadd<0xB1>(p);   // quad_perm [1,0,3,2]
  p = dppadd<0x4E>(p);   // quad_perm [2,3,0,1]
  p = dppadd<0x141>(p);  // row_half_mirror
  p = dppadd<0x140>(p);  // row_mirror
  return p;
}
__device__ __forceinline__ float red64(float p) {
  p = red16d(p);
  p += __shfl_xor(p, 16); p += __shfl_xor(p, 32);
  return p;
}

__device__ __forceinline__ unsigned f2bf(float f) {  // rne f32->bf16
  unsigned u = __float_as_uint(f);
  return (u + 0x7fffu + ((u >> 16) & 1u)) >> 16;
}
__device__ __forceinline__ float bflo(unsigned u) { return __uint_as_float(u << 16); }
__device__ __forceinline__ float bfhi(unsigned u) { return __uint_as_float(u & 0xffff0000u); }

__device__ __forceinline__ half2v u2h(unsigned u) {
  return __builtin_bit_cast(half2v, u);
}
// dot of 8 f16 pairs: xh holds 4 packed k-pairs, w0..w3 packed Wl columns
__device__ __forceinline__ float dot8h(uint4 xh, unsigned w0, unsigned w1,
                                       unsigned w2, unsigned w3) {
#if __has_builtin(__builtin_amdgcn_fdot2)
  float s = __builtin_amdgcn_fdot2(u2h(xh.x), u2h(w0), 0.f, false);
  s = __builtin_amdgcn_fdot2(u2h(xh.y), u2h(w1), s, false);
  s = __builtin_amdgcn_fdot2(u2h(xh.z), u2h(w2), s, false);
  s = __builtin_amdgcn_fdot2(u2h(xh.w), u2h(w3), s, false);
  return s;
#else
  float s = 0.f;
  half2v a;
  a = u2h(xh.x); { half2v b = u2h(w0); s += (float)a.x*(float)b.x + (float)a.y*(float)b.y; }
  a = u2h(xh.y); { half2v b = u2h(w1); s += (float)a.x*(float)b.x + (float)a.y*(float)b.y; }
  a = u2h(xh.z); { half2v b = u2h(w2); s += (float)a.x*(float)b.x + (float)a.y*(float)b.y; }
  a = u2h(xh.w); { half2v b = u2h(w3); s += (float)a.x*(float)b.x + (float)a.y*(float)b.y; }
  return s;
#endif
}

// ---------------- K1: per-dst degree + edge_attr sum ----------------
__global__ void k_hist(const int* __restrict__ dst, const float* __restrict__ ea,
                       int* __restrict__ deg, float* __restrict__ easum) {
  int e = blockIdx.x * 256 + threadIdx.x;
  if (e >= N_EDGES) return;
  int d = dst[e];
  atomicAdd(&deg[d], 1);
  atomicAdd(&easum[d], ea[e]);
}

// ---------------- K2: exclusive scan of quad-padded lengths ----------------
__global__ void k_scan(const int* __restrict__ deg, int* __restrict__ off2) {
  __shared__ int part[1024];
  int t = threadIdx.x;
  const int CH = (N_NODES + 1023) / 1024;  // 49
  int lo = t * CH, hi = min(lo + CH, N_NODES);
  int s = 0;
  for (int i = lo; i < hi; ++i) s += (deg[i] + 4) & ~3;   // +self, pad to mult of 4
  part[t] = s;
  __syncthreads();
  for (int off = 1; off < 1024; off <<= 1) {
    int v = (t >= off) ? part[t - off] : 0;
    __syncthreads();
    part[t] += v;
    __syncthreads();
  }
  int run = (t == 0) ? 0 : part[t - 1];
  for (int i = lo; i < hi; ++i) { off2[i] = run; run += (deg[i] + 4) & ~3; }
  if (t == 1023) off2[N_NODES] = part[1023];
}

// ---------------- K3: write self-loop entry (+sentinel pads) ----------------
__global__ void k_self(const int* __restrict__ deg, const float* __restrict__ easum,
                       const int* __restrict__ off2,
                       int* __restrict__ ssrc, float* __restrict__ sea) {
  int n = blockIdx.x * 256 + threadIdx.x;
  if (n >= N_NODES) return;
  int b = off2[n], d = deg[n];
  ssrc[b + d] = n;
  sea[b + d]  = easum[n] / fmaxf((float)d, 1.0f);
  int pad = (d + 4) & ~3;
  for (int j = d + 1; j < pad; ++j) { ssrc[b + j] = -1; sea[b + j] = 0.f; }
}

// ---------------- K4: counting-sort scatter (edges grouped by dst) ----------------
__global__ void k_scatter(const int* __restrict__ src, const int* __restrict__ dst,
                          const float* __restrict__ ea, const int* __restrict__ off2,
                          int* __restrict__ cursor, int* __restrict__ ssrc,
                          float* __restrict__ sea) {
  int e = blockIdx.x * 256 + threadIdx.x;
  if (e >= N_EDGES) return;
  int d = dst[e];
  int pos = off2[d] + atomicAdd(&cursor[d], 1);
  ssrc[pos] = src[e];
  sea[pos]  = ea[e];
}

// ---------------- K5a: x -> packed f16 pairs (uint4 per node) ----------------
__global__ void k_xprep(const float* __restrict__ x, uint4* __restrict__ xh) {
  int n = blockIdx.x * 256 + threadIdx.x;
  if (n >= N_NODES) return;
  float4 a = *(const float4*)(x + n * 8);
  float4 b = *(const float4*)(x + n * 8 + 4);
  half2v p0 = {(_Float16)a.x, (_Float16)a.y};
  half2v p1 = {(_Float16)a.z, (_Float16)a.w};
  half2v p2 = {(_Float16)b.x, (_Float16)b.y};
  half2v p3 = {(_Float16)b.z, (_Float16)b.w};
  xh[n] = make_uint4(__builtin_bit_cast(unsigned, p0), __builtin_bit_cast(unsigned, p1),
                     __builtin_bit_cast(unsigned, p2), __builtin_bit_cast(unsigned, p3));
}

// ---------------- K5b: Wl1 -> packed f16 k-pairs [kp][ch] ----------------
__global__ void k_wlprep(const float* __restrict__ Wl, unsigned* __restrict__ Wlh) {
  int kp = blockIdx.x, c = threadIdx.x;   // 4 x 256
  half2v h = {(_Float16)Wl[(2 * kp) * 256 + c], (_Float16)Wl[(2 * kp + 1) * 256 + c]};
  Wlh[kp * 256 + c] = __builtin_bit_cast(unsigned, h);
}

// ---------------- K5c: transpose+cast weights [Wl2|Wr2] -> Btp[256][256] bf16 -----
__global__ void k_wprep(const float* __restrict__ Wl2, const float* __restrict__ Wr2,
                        unsigned short* __restrict__ Btp) {
  int nIdx = blockIdx.x;           // output col 0..255
  int k = threadIdx.x;             // 0..255
  float v = (nIdx < 128) ? Wl2[k * 128 + nIdx] : Wr2[k * 128 + (nIdx - 128)];
  Btp[nIdx * 256 + k] = (unsigned short)f2bf(v);
}

// ---------------- K6: fused GATv2 layer 1 + bias + LN + ELU -> h1 (bf16) ----------
// one wave per node; lane owns 4 channels (c0=lane*4), head = lane/16.
// xl[src] recomputed per edge via f16 dot2 from packed x (wave-uniform 16B load).
__global__ __launch_bounds__(256) void k_gat1(
    const float* __restrict__ x, const uint4* __restrict__ xh16,
    const unsigned* __restrict__ Wlh,
    const float* __restrict__ Wr, const float* __restrict__ We,
    const float* __restrict__ att,
    const float* __restrict__ b1, const float* __restrict__ g1,
    const float* __restrict__ be1,
    const int* __restrict__ off2, const int* __restrict__ ssrc,
    const float* __restrict__ sea, unsigned* __restrict__ h1b) {
  int lane = threadIdx.x & 63;
  int n = blockIdx.x * 4 + (threadIdx.x >> 6);
  int c0 = lane * 4;

  float4 wev = *(const float4*)(We + c0);
  float4 atv = *(const float4*)(att + c0);

  float xn[8];
  {
    float4 a = *(const float4*)(x + n * 8);
    float4 b = *(const float4*)(x + n * 8 + 4);
    xn[0]=a.x; xn[1]=a.y; xn[2]=a.z; xn[3]=a.w;
    xn[4]=b.x; xn[5]=b.y; xn[6]=b.z; xn[7]=b.w;
  }
  float xr0=0.f, xr1=0.f, xr2=0.f, xr3=0.f;
#pragma unroll
  for (int k = 0; k < 8; ++k) {
    float4 wr = *(const float4*)(Wr + k * 256 + c0);
    xr0 += xn[k]*wr.x; xr1 += xn[k]*wr.y; xr2 += xn[k]*wr.z; xr3 += xn[k]*wr.w;
  }
  // packed f16 Wl columns for this lane's 4 channels (4 k-pairs each)
  uint4 wk0 = *(const uint4*)(Wlh + 0 * 256 + c0);
  uint4 wk1 = *(const uint4*)(Wlh + 1 * 256 + c0);
  uint4 wk2 = *(const uint4*)(Wlh + 2 * 256 + c0);
  uint4 wk3 = *(const uint4*)(Wlh + 3 * 256 + c0);

  int beg = off2[n];
  int pairs = (off2[n + 1] - beg) >> 1;   // even, >= 2 (self + pads)

  float den = 0.f, ac0=0.f, ac1=0.f, ac2=0.f, ac3=0.f;

  int sA = ssrc[beg], sB = ssrc[beg + 1];
  float eA = sea[beg], eB = sea[beg + 1];
  uint4 xA = xh16[max(sA, 0)];
  uint4 xB = xh16[max(sB, 0)];

  for (int p = 0; p < pairs; ++p) {
    int   csA = sA, csB = sB;
    float ceA = eA, ceB = eB;
    uint4 cxA = xA, cxB = xB;
    if (p + 1 < pairs) {
      int j = beg + 2 * (p + 1);
      sA = ssrc[j]; sB = ssrc[j + 1];
      eA = sea[j];  eB = sea[j + 1];
      xA = xh16[max(sA, 0)];
      xB = xh16[max(sB, 0)];
    }
    // xl per edge: 4 ch x 4 dot2 each
    float vA0 = dot8h(cxA, wk0.x, wk1.x, wk2.x, wk3.x);
    float vA1 = dot8h(cxA, wk0.y, wk1.y, wk2.y, wk3.y);
    float vA2 = dot8h(cxA, wk0.z, wk1.z, wk2.z, wk3.z);
    float vA3 = dot8h(cxA, wk0.w, wk1.w, wk2.w, wk3.w);
    float vB0 = dot8h(cxB, wk0.x, wk1.x, wk2.x, wk3.x);
    float vB1 = dot8h(cxB, wk0.y, wk1.y, wk2.y, wk3.y);
    float vB2 = dot8h(cxB, wk0.z, wk1.z, wk2.z, wk3.z);
    float vB3 = dot8h(cxB, wk0.w, wk1.w, wk2.w, wk3.w);

    // m = v + (xr + e*We); leaky = max(m, 0.2m)
    float mA0 = vA0 + fmaf(ceA, wev.x, xr0); mA0 = fmaxf(mA0, 0.2f*mA0);
    float mA1 = vA1 + fmaf(ceA, wev.y, xr1); mA1 = fmaxf(mA1, 0.2f*mA1);
    float mA2 = vA2 + fmaf(ceA, wev.z, xr2); mA2 = fmaxf(mA2, 0.2f*mA2);
    float mA3 = vA3 + fmaf(ceA, wev.w, xr3); mA3 = fmaxf(mA3, 0.2f*mA3);
    float mB0 = vB0 + fmaf(ceB, wev.x, xr0); mB0 = fmaxf(mB0, 0.2f*mB0);
    float mB1 = vB1 + fmaf(ceB, wev.y, xr1); mB1 = fmaxf(mB1, 0.2f*mB1);
    float mB2 = vB2 + fmaf(ceB, wev.z, xr2); mB2 = fmaxf(mB2, 0.2f*mB2);
    float mB3 = vB3 + fmaf(ceB, wev.w, xr3); mB3 = fmaxf(mB3, 0.2f*mB3);

    float pA = mA0*atv.x + mA1*atv.y + mA2*atv.z + mA3*atv.w;
    float pB = mB0*atv.x + mB1*atv.y + mB2*atv.z + mB3*atv.w;
    pA = red16d(pA);               // per-head 16-lane DPP reduce
    pB = red16d(pB);

    float wA = (csA >= 0) ? __expf(pA) : 0.f;
    float wB = (csB >= 0) ? __expf(pB) : 0.f;
    den += wA + wB;
    ac0 = fmaf(wA, vA0, fmaf(wB, vB0, ac0));
    ac1 = fmaf(wA, vA1, fmaf(wB, vB1, ac1));
    ac2 = fmaf(wA, vA2, fmaf(wB, vB2, ac2));
    ac3 = fmaf(wA, vA3, fmaf(wB, vB3, ac3));
  }

  float inv = 1.0f / (den + 1e-16f);
  float4 bv = *(const float4*)(b1 + c0);
  float o0 = ac0*inv + bv.x, o1 = ac1*inv + bv.y;
  float o2 = ac2*inv + bv.z, o3 = ac3*inv + bv.w;
  float mu = red64(o0 + o1 + o2 + o3) * (1.0f / 256.0f);
  float d0 = o0-mu, d1 = o1-mu, d2 = o2-mu, d3 = o3-mu;
  float rstd = rsqrtf(red64(d0*d0 + d1*d1 + d2*d2 + d3*d3) * (1.0f/256.0f) + LN_EPS);
  float4 gv  = *(const float4*)(g1 + c0);
  float4 bev = *(const float4*)(be1 + c0);
  float y0 = d0*rstd*gv.x + bev.x; y0 = y0 > 0.f ? y0 : __expf(y0) - 1.0f;
  float y1 = d1*rstd*gv.y + bev.y; y1 = y1 > 0.f ? y1 : __expf(y1) - 1.0f;
  float y2 = d2*rstd*gv.z + bev.z; y2 = y2 > 0.f ? y2 : __expf(y2) - 1.0f;
  float y3 = d3*rstd*gv.w + bev.w; y3 = y3 > 0.f ? y3 : __expf(y3) - 1.0f;
  unsigned lo = f2bf(y0) | (f2bf(y1) << 16);
  unsigned hi = f2bf(y2) | (f2bf(y3) << 16);
  *(uint2*)(h1b + (size_t)n * 128 + lane * 2) = make_uint2(lo, hi);
}

// ---------------- K7: MFMA GEMM  [xl2|xr2] = h1(bf16) @ Btp^T ----------------
__global__ __launch_bounds__(256) void k_gemm2(
    const unsigned* __restrict__ h1b, const unsigned short* __restrict__ Btp,
    unsigned short* __restrict__ xl2b, float* __restrict__ xr2) {
  __shared__ unsigned short Ash[64][264];
  __shared__ unsigned short Bsh[64][264];
  int t = threadIdx.x;
  int bm0 = blockIdx.x * 64;
  int n0  = blockIdx.y * 64;

#pragma unroll
  for (int i = 0; i < 8; ++i) {
    int idx = t + 256 * i;          // uint4 index; 2048 total
    int row = idx >> 5, c4 = idx & 31;
    int gm = bm0 + row;
    uint4 va = (gm < N_NODES) ? *(const uint4*)(h1b + (size_t)gm * 128 + c4 * 4)
                              : make_uint4(0,0,0,0);
    *(uint4*)(&Ash[row][c4 * 8]) = va;
    uint4 vb = *(const uint4*)((const unsigned*)Btp + (size_t)(n0 + row) * 128 + c4 * 4);
    *(uint4*)(&Bsh[row][c4 * 8]) = vb;
  }
  __syncthreads();

  int lane = t & 63, w = t >> 6;
  int lm = lane & 15, lk = (lane >> 4) * 8;
  f32x4 acc[4];
#pragma unroll
  for (int i = 0; i < 4; ++i) acc[i] = (f32x4){0.f,0.f,0.f,0.f};

#pragma unroll
  for (int kk = 0; kk < 8; ++kk) {
    bf16x8 a = *(const bf16x8*)(&Ash[16*w + lm][kk*32 + lk]);
#pragma unroll
    for (int tt = 0; tt < 4; ++tt) {
      bf16x8 b = *(const bf16x8*)(&Bsh[16*tt + lm][kk*32 + lk]);
      acc[tt] = __builtin_amdgcn_mfma_f32_16x16x32_bf16(a, b, acc[tt], 0, 0, 0);
    }
  }

#pragma unroll
  for (int tt = 0; tt < 4; ++tt) {
#pragma unroll
    for (int r = 0; r < 4; ++r) {
      int node = bm0 + 16*w + (lane >> 4) * 4 + r;
      if (node < N_NODES) {
        int colg = n0 + tt * 16 + lm;
        float v = acc[tt][r];
        if (colg < 128) xl2b[(size_t)node * 128 + colg] = (unsigned short)f2bf(v);
        else            xr2 [(size_t)node * 128 + (colg - 128)] = v;
      }
    }
  }
}

// ---------------- K8: fused GATv2 layer 2 + bias + LN + ELU + pooled atomics ------
// one wave per node; 16 lanes per edge (8 ch/lane), 4 edges per iteration.
__global__ __launch_bounds__(256) void k_gat2(
    const unsigned* __restrict__ xl2b, const float* __restrict__ xr2,
    const float* __restrict__ We, const float* __restrict__ att,
    const float* __restrict__ b2, const float* __restrict__ g2,
    const float* __restrict__ be2,
    const int* __restrict__ off2, const int* __restrict__ ssrc,
    const float* __restrict__ sea,
    const int* __restrict__ batch,
    float* __restrict__ pool, float* __restrict__ cnt) {
  int tid = threadIdx.x;
  int lane = tid & 63, wid = tid >> 6;
  int row = lane >> 4, col = lane & 15;
  int n = blockIdx.x * 4 + wid;
  int c0 = col * 8;               // 8 channels per lane
  int cu0 = col * 4;              // uint offset into bf16-packed row

  float wev[8], at[8], xr[8];
  *(float4*)(wev)     = *(const float4*)(We + c0);
  *(float4*)(wev + 4) = *(const float4*)(We + c0 + 4);
  *(float4*)(at)      = *(const float4*)(att + c0);
  *(float4*)(at + 4)  = *(const float4*)(att + c0 + 4);
  *(float4*)(xr)      = *(const float4*)(xr2 + (size_t)n * 128 + c0);
  *(float4*)(xr + 4)  = *(const float4*)(xr2 + (size_t)n * 128 + c0 + 4);

  int beg = off2[n];
  int quads = (off2[n + 1] - beg) >> 2;   // >= 1

  float den = 0.f;
  float ac[8] = {0,0,0,0,0,0,0,0};

  // depth-2 quad pipeline; each row of 16 lanes owns one edge per quad
  int s0 = ssrc[beg + row];
  float e0 = sea[beg + row];
  uint4 u0 = *(const uint4*)(xl2b + (size_t)max(s0, 0) * 64 + cu0);
  int s1 = -1; float e1 = 0.f; uint4 u1 = make_uint4(0,0,0,0);
  if (quads > 1) {
    s1 = ssrc[beg + 4 + row]; e1 = sea[beg + 4 + row];
    u1 = *(const uint4*)(xl2b + (size_t)max(s1, 0) * 64 + cu0);
  }

  for (int q = 0; q < quads; ++q) {
    int cs = s0; float ce = e0; uint4 cu = u0;
    s0 = s1; e0 = e1; u0 = u1;
    if (q + 2 < quads) {
      int j = beg + (q + 2) * 4 + row;
      s1 = ssrc[j]; e1 = sea[j];
      u1 = *(const uint4*)(xl2b + (size_t)max(s1, 0) * 64 + cu0);
    }
    float v[8];
    v[0]=bflo(cu.x); v[1]=bfhi(cu.x); v[2]=bflo(cu.y); v[3]=bfhi(cu.y);
    v[4]=bflo(cu.z); v[5]=bfhi(cu.z); v[6]=bflo(cu.w); v[7]=bfhi(cu.w);
    float p = 0.f;
#pragma unroll
    for (int j = 0; j < 8; ++j) {
      float m = v[j] + fmaf(ce, wev[j], xr[j]);
      m = fmaxf(m, 0.2f * m);
      p = fmaf(m, at[j], p);
    }
    p = red16d(p);                  // per-edge reduce over its 16-lane row
    float w = (cs >= 0) ? __expf(p) : 0.f;
    den += w;
#pragma unroll
    for (int j = 0; j < 8; ++j) ac[j] = fmaf(w, v[j], ac[j]);
  }
  // combine 4 rows
  den += __shfl_xor(den, 16); den += __shfl_xor(den, 32);
#pragma unroll
  for (int j = 0; j < 8; ++j) {
    ac[j] += __shfl_xor(ac[j], 16);
    ac[j] += __shfl_xor(ac[j], 32);
  }

  float inv = 1.0f / (den + 1e-16f);
  float o[8], y[8];
  float bv[8], gv[8], bev[8];
  *(float4*)(bv)      = *(const float4*)(b2 + c0);
  *(float4*)(bv + 4)  = *(const float4*)(b2 + c0 + 4);
  *(float4*)(gv)      = *(const float4*)(g2 + c0);
  *(float4*)(gv + 4)  = *(const float4*)(g2 + c0 + 4);
  *(float4*)(bev)     = *(const float4*)(be2 + c0);
  *(float4*)(bev + 4) = *(const float4*)(be2 + c0 + 4);
  float osum = 0.f;
#pragma unroll
  for (int j = 0; j < 8; ++j) { o[j] = ac[j] * inv + bv[j]; osum += o[j]; }
  // each channel appears in 4 rows -> divide by 512
  float mu = red64(osum) * (1.0f / 512.0f);
  float vsum = 0.f;
#pragma unroll
  for (int j = 0; j < 8; ++j) { o[j] -= mu; vsum += o[j] * o[j]; }
  float rstd = rsqrtf(red64(vsum) * (1.0f / 512.0f) + LN_EPS);
#pragma unroll
  for (int j = 0; j < 8; ++j) {
    float t = o[j] * rstd * gv[j] + bev[j];
    y[j] = t > 0.f ? t : __expf(t) - 1.0f;
  }

  // block-level pool dedup (batch sorted -> usually 1 graph per block)
  __shared__ float pbuf[4][128];
  __shared__ int gbuf[4];
  if (row == 0) {
#pragma unroll
    for (int j = 0; j < 8; ++j) pbuf[wid][c0 + j] = y[j];
  }
  if (lane == 0) gbuf[wid] = batch[n];
  __syncthreads();
  if (wid == 0) {
    int r = blockIdx.x & (NREP - 1);
    int ch = lane;                       // handles ch and ch+64
    float acc0 = pbuf[0][ch], acc1 = pbuf[0][ch+64];
    int cg = gbuf[0], cn = 1;
#pragma unroll
    for (int i = 1; i < 4; ++i) {
      if (gbuf[i] == cg) { acc0 += pbuf[i][ch]; acc1 += pbuf[i][ch+64]; cn++; }
      else {
        float* pp = pool + ((size_t)(r * N_GRAPHS + cg)) * 128;
        atomicAdd(pp + ch, acc0); atomicAdd(pp + ch + 64, acc1);
        if (lane == 0) atomicAdd(&cnt[r * N_GRAPHS + cg], (float)cn);
        cg = gbuf[i]; acc0 = pbuf[i][ch]; acc1 = pbuf[i][ch+64]; cn = 1;
      }
    }
    float* pp = pool + ((size_t)(r * N_GRAPHS + cg)) * 128;
    atomicAdd(pp + ch, acc0); atomicAdd(pp + ch + 64, acc1);
    if (lane == 0) atomicAdd(&cnt[r * N_GRAPHS + cg], (float)cn);
  }
}

// ---------------- K9: reduce replicas, divide by count ----------------
__global__ void k_final(const float* __restrict__ pool, const float* __restrict__ cnt,
                        float* __restrict__ out) {
  int idx = blockIdx.x * 256 + threadIdx.x;
  if (idx >= N_GRAPHS * 128) return;
  int g = idx >> 7, c = idx & 127;
  float s = 0.f, nn = 0.f;
#pragma unroll
  for (int r = 0; r < NREP; ++r) {
    s  += pool[((size_t)(r * N_GRAPHS + g)) * 128 + c];
    nn += cnt[r * N_GRAPHS + g];
  }
  out[idx] = s / fmaxf(nn, 1.0f);
}

// ---------------- launch ----------------
extern "C" void kernel_launch(void* const* d_in, const int* in_sizes, int n_in,
                              void* d_out, int out_size, void* d_ws, size_t ws_size,
                              hipStream_t stream) {
  const float* x    = (const float*)d_in[0];
  const int*   ei   = (const int*)  d_in[1];
  const float* ea   = (const float*)d_in[2];
  const int*   batch= (const int*)  d_in[3];
  const float* Wl1  = (const float*)d_in[4];
  const float* Wr1  = (const float*)d_in[5];
  const float* We1  = (const float*)d_in[6];
  const float* att1 = (const float*)d_in[7];
  const float* b1   = (const float*)d_in[8];
  const float* g1   = (const float*)d_in[9];
  const float* be1  = (const float*)d_in[10];
  const float* Wl2  = (const float*)d_in[11];
  const float* Wr2  = (const float*)d_in[12];
  const float* We2  = (const float*)d_in[13];
  const float* att2 = (const float*)d_in[14];
  const float* b2   = (const float*)d_in[15];
  const float* g2   = (const float*)d_in[16];
  const float* be2  = (const float*)d_in[17];
  const int* srcp = ei;
  const int* dstp = ei + N_EDGES;

  const int MAXE2 = N_EDGES + 4 * N_NODES;

  char* ws = (char*)d_ws;
  size_t off = 0;
  auto alloc = [&](size_t bytes) {
    char* p = ws + off; off += (bytes + 15) & ~(size_t)15; return p;
  };
  int*            deg   = (int*)           alloc((size_t)N_NODES * 4);
  float*          easum = (float*)         alloc((size_t)N_NODES * 4);
  int*            cursor= (int*)           alloc((size_t)N_NODES * 4);
  int*            off2  = (int*)           alloc((size_t)(N_NODES + 1) * 4);
  int*            ssrc  = (int*)           alloc((size_t)MAXE2 * 4);
  float*          sea   = (float*)         alloc((size_t)MAXE2 * 4);
  uint4*          xh16  = (uint4*)         alloc((size_t)N_NODES * 16);
  unsigned*       Wlh   = (unsigned*)      alloc((size_t)4 * 256 * 4);
  unsigned*       h1b   = (unsigned*)      alloc((size_t)N_NODES * 128 * 4);  // bf16 256ch
  unsigned short* xl2b  = (unsigned short*)alloc((size_t)N_NODES * 128 * 2);  // bf16 128ch
  float*          xr2   = (float*)         alloc((size_t)N_NODES * 128 * 4);
  unsigned short* Btp   = (unsigned short*)alloc((size_t)256 * 256 * 2);
  float*          pool  = (float*)         alloc((size_t)NREP * N_GRAPHS * 128 * 4);
  float*          cnt   = (float*)         alloc((size_t)NREP * N_GRAPHS * 4);

  (void)hipMemsetAsync(deg, 0, (char*)off2 - (char*)deg, stream);   // deg, easum, cursor
  (void)hipMemsetAsync(pool, 0, ((char*)cnt + (((size_t)NREP*N_GRAPHS*4 + 15) & ~(size_t)15))
                           - (char*)pool, stream);

  k_hist   <<<N_EDGES / 256, 256, 0, stream>>>(dstp, ea, deg, easum);
  k_xprep  <<<(N_NODES + 255) / 256, 256, 0, stream>>>(x, xh16);
  k_wlprep <<<4, 256, 0, stream>>>(Wl1, Wlh);
  k_wprep  <<<256, 256, 0, stream>>>(Wl2, Wr2, Btp);
  k_scan   <<<1, 1024, 0, stream>>>(deg, off2);
  k_self   <<<(N_NODES + 255) / 256, 256, 0, stream>>>(deg, easum, off2, ssrc, sea);
  k_scatter<<<N_EDGES / 256, 256, 0, stream>>>(srcp, dstp, ea, off2, cursor, ssrc, sea);
  k_gat1   <<<N_NODES / 4, 256, 0, stream>>>(x, xh16, Wlh, Wr1, We1, att1, b1, g1, be1,
                                             off2, ssrc, sea, h1b);
  dim3 g7((N_NODES + 63) / 64, 4);
  k_gemm2  <<<g7, 256, 0, stream>>>(h1b, Btp, xl2b, xr2);
  k_gat2   <<<N_NODES / 4, 256, 0, stream>>>((const unsigned*)xl2b, xr2, We2, att2,
                                             b2, g2, be2,
                                             off2, ssrc, sea, batch, pool, cnt);
  k_final  <<<(N_GRAPHS * 128) / 256, 256, 0, stream>>>(pool, cnt, (float*)d_out);
}

// Round 7
// 454.029 us; speedup vs baseline: 1.7003x; 1.1901x over previous
//
#include <hip/hip_runtime.h>
#include <math.h>

#define N_NODES 50000
#define N_EDGES 800000
#define N_GRAPHS 64
#define NREP 32
#define LN_EPS 1e-5f
#define SCAN_BLKS 196          // ceil(50000/256)

typedef __attribute__((ext_vector_type(8))) short bf16x8;
typedef __attribute__((ext_vector_type(4))) float f32x4;
typedef __attribute__((ext_vector_type(2))) _Float16 half2v;

// ---------------- DPP-based reductions (no LDS latency) ----------------
template <int CTRL>
__device__ __forceinline__ float dppadd(float v) {
  int t = __builtin_amdgcn_update_dpp(0, __float_as_int(v), CTRL, 0xF, 0xF, true);
  return v + __int_as_float(t);
}
__device__ __forceinline__ float red16d(float p) {
  p = dppadd<0xB1>(p);   // quad_perm [1,0,3,2]
  p = dppadd<0x4E>(p);   // quad_perm [2,3,0,1]
  p = dppadd<0x141>(p);  // row_half_mirror
  p = dppadd<0x140>(p);  // row_mirror
  return p;
}
__device__ __forceinline__ float red64(float p) {
  p = red16d(p);
  p += __shfl_xor(p, 16); p += __shfl_xor(p, 32);
  return p;
}

__device__ __forceinline__ unsigned f2bf(float f) {  // rne f32->bf16
  unsigned u = __float_as_uint(f);
  return (u + 0x7fffu + ((u >> 16) & 1u)) >> 16;
}
__device__ __forceinline__ float bflo(unsigned u) { return __uint_as_float(u << 16); }
__device__ __forceinline__ float bfhi(unsigned u) { return __uint_as_float(u & 0xffff0000u); }

__device__ __forceinline__ half2v u2h(unsigned u) {
  return __builtin_bit_cast(half2v, u);
}
__device__ __forceinline__ float dot8h(uint4 xh, unsigned w0, unsigned w1,
                                       unsigned w2, unsigned w3) {
#if __has_builtin(__builtin_amdgcn_fdot2)
  float s = __builtin_amdgcn_fdot2(u2h(xh.x), u2h(w0), 0.f, false);
  s = __builtin_amdgcn_fdot2(u2h(xh.y), u2h(w1), s, false);
  s = __builtin_amdgcn_fdot2(u2h(xh.z), u2h(w2), s, false);
  s = __builtin_amdgcn_fdot2(u2h(xh.w), u2h(w3), s, false);
  return s;
#else
  float s = 0.f;
  half2v a;
  a = u2h(xh.x); { half2v b = u2h(w0); s += (float)a.x*(float)b.x + (float)a.y*(float)b.y; }
  a = u2h(xh.y); { half2v b = u2h(w1); s += (float)a.x*(float)b.x + (float)a.y*(float)b.y; }
  a = u2h(xh.z); { half2v b = u2h(w2); s += (float)a.x*(float)b.x + (float)a.y*(float)b.y; }
  a = u2h(xh.w); { half2v b = u2h(w3); s += (float)a.x*(float)b.x + (float)a.y*(float)b.y; }
  return s;
#endif
}

// ---------------- K1: per-dst degree + edge_attr sum ----------------
__global__ void k_hist(const int* __restrict__ dst, const float* __restrict__ ea,
                       int* __restrict__ deg, float* __restrict__ easum) {
  int e = blockIdx.x * 256 + threadIdx.x;
  if (e >= N_EDGES) return;
  int d = dst[e];
  atomicAdd(&deg[d], 1);
  atomicAdd(&easum[d], ea[e]);
}

// ---------------- K2: multi-block exclusive scan of quad-padded lengths ----------
__global__ void k_scanA(const int* __restrict__ deg, int* __restrict__ part) {
  int t = threadIdx.x;
  int i = blockIdx.x * 256 + t;
  int len = (i < N_NODES) ? ((deg[i] + 4) & ~3) : 0;
  __shared__ int sm[256];
  sm[t] = len; __syncthreads();
  for (int o = 128; o > 0; o >>= 1) {
    if (t < o) sm[t] += sm[t + o];
    __syncthreads();
  }
  if (t == 0) part[blockIdx.x] = sm[0];
}
__global__ void k_scanB(const int* __restrict__ part, int* __restrict__ base) {
  int t = threadIdx.x;                 // 256 threads, 1 block
  __shared__ int sm[256];
  int v = (t < SCAN_BLKS) ? part[t] : 0;
  sm[t] = v; __syncthreads();
  for (int o = 1; o < 256; o <<= 1) {
    int u = (t >= o) ? sm[t - o] : 0;
    __syncthreads();
    sm[t] += u;
    __syncthreads();
  }
  base[t] = (t == 0) ? 0 : sm[t - 1];  // exclusive
}
__global__ void k_scanC(const int* __restrict__ deg, const int* __restrict__ base,
                        int* __restrict__ off2) {
  int t = threadIdx.x;
  int i = blockIdx.x * 256 + t;
  int len = (i < N_NODES) ? ((deg[i] + 4) & ~3) : 0;
  __shared__ int sm[256];
  sm[t] = len; __syncthreads();
  for (int o = 1; o < 256; o <<= 1) {
    int u = (t >= o) ? sm[t - o] : 0;
    __syncthreads();
    sm[t] += u;
    __syncthreads();
  }
  int incl = sm[t];
  if (i < N_NODES) off2[i] = base[blockIdx.x] + incl - len;
  if (i == N_NODES - 1) off2[N_NODES] = base[blockIdx.x] + incl;
}

// ---------------- K3: write self-loop entry (+sentinel pads) ----------------
__global__ void k_self(const int* __restrict__ deg, const float* __restrict__ easum,
                       const int* __restrict__ off2,
                       int* __restrict__ ssrc, float* __restrict__ sea) {
  int n = blockIdx.x * 256 + threadIdx.x;
  if (n >= N_NODES) return;
  int b = off2[n], d = deg[n];
  ssrc[b + d] = n;
  sea[b + d]  = easum[n] / fmaxf((float)d, 1.0f);
  int pad = (d + 4) & ~3;
  for (int j = d + 1; j < pad; ++j) { ssrc[b + j] = -1; sea[b + j] = 0.f; }
}

// ---------------- K4: counting-sort scatter (edges grouped by dst) ----------------
__global__ void k_scatter(const int* __restrict__ src, const int* __restrict__ dst,
                          const float* __restrict__ ea, const int* __restrict__ off2,
                          int* __restrict__ cursor, int* __restrict__ ssrc,
                          float* __restrict__ sea) {
  int e = blockIdx.x * 256 + threadIdx.x;
  if (e >= N_EDGES) return;
  int d = dst[e];
  int pos = off2[d] + atomicAdd(&cursor[d], 1);
  ssrc[pos] = src[e];
  sea[pos]  = ea[e];
}

// ---------------- K5a: x -> packed f16 pairs (uint4 per node) ----------------
__global__ void k_xprep(const float* __restrict__ x, uint4* __restrict__ xh) {
  int n = blockIdx.x * 256 + threadIdx.x;
  if (n >= N_NODES) return;
  float4 a = *(const float4*)(x + n * 8);
  float4 b = *(const float4*)(x + n * 8 + 4);
  half2v p0 = {(_Float16)a.x, (_Float16)a.y};
  half2v p1 = {(_Float16)a.z, (_Float16)a.w};
  half2v p2 = {(_Float16)b.x, (_Float16)b.y};
  half2v p3 = {(_Float16)b.z, (_Float16)b.w};
  xh[n] = make_uint4(__builtin_bit_cast(unsigned, p0), __builtin_bit_cast(unsigned, p1),
                     __builtin_bit_cast(unsigned, p2), __builtin_bit_cast(unsigned, p3));
}

// ---------------- K5b: Wl1 -> packed f16 k-pairs [kp][ch] ----------------
__global__ void k_wlprep(const float* __restrict__ Wl, unsigned* __restrict__ Wlh) {
  int kp = blockIdx.x, c = threadIdx.x;   // 4 x 256
  half2v h = {(_Float16)Wl[(2 * kp) * 256 + c], (_Float16)Wl[(2 * kp + 1) * 256 + c]};
  Wlh[kp * 256 + c] = __builtin_bit_cast(unsigned, h);
}

// ---------------- K5c: transpose+cast weights [Wl2|Wr2] -> Btp[256][256] bf16 -----
__global__ void k_wprep(const float* __restrict__ Wl2, const float* __restrict__ Wr2,
                        unsigned short* __restrict__ Btp) {
  int nIdx = blockIdx.x;           // output col 0..255
  int k = threadIdx.x;             // 0..255
  float v = (nIdx < 128) ? Wl2[k * 128 + nIdx] : Wr2[k * 128 + (nIdx - 128)];
  Btp[nIdx * 256 + k] = (unsigned short)f2bf(v);
}

// ---------------- K6: fused GATv2 layer 1 + bias + LN + ELU -> h1 (bf16) ----------
// one wave per node; lane owns 4 channels; ALL per-edge CSR state is wave-uniform
// and forced scalar via readfirstlane -> s_load path, freeing VALU issue slots.
__global__ __launch_bounds__(256) void k_gat1(
    const float* __restrict__ x, const uint4* __restrict__ xh16,
    const unsigned* __restrict__ Wlh,
    const float* __restrict__ Wr, const float* __restrict__ We,
    const float* __restrict__ att,
    const float* __restrict__ b1, const float* __restrict__ g1,
    const float* __restrict__ be1,
    const int* __restrict__ off2, const int* __restrict__ ssrc,
    const float* __restrict__ sea, unsigned* __restrict__ h1b) {
  int lane = threadIdx.x & 63;
  int wv = __builtin_amdgcn_readfirstlane(threadIdx.x >> 6);  // scalar wave id
  int n = blockIdx.x * 4 + wv;                                 // scalar node id
  int c0 = lane * 4;

  float4 wev = *(const float4*)(We + c0);
  float4 atv = *(const float4*)(att + c0);

  float xn[8];
  {
    float4 a = *(const float4*)(x + n * 8);
    float4 b = *(const float4*)(x + n * 8 + 4);
    xn[0]=a.x; xn[1]=a.y; xn[2]=a.z; xn[3]=a.w;
    xn[4]=b.x; xn[5]=b.y; xn[6]=b.z; xn[7]=b.w;
  }
  float xr0=0.f, xr1=0.f, xr2=0.f, xr3=0.f;
#pragma unroll
  for (int k = 0; k < 8; ++k) {
    float4 wr = *(const float4*)(Wr + k * 256 + c0);
    xr0 += xn[k]*wr.x; xr1 += xn[k]*wr.y; xr2 += xn[k]*wr.z; xr3 += xn[k]*wr.w;
  }
  uint4 wk0 = *(const uint4*)(Wlh + 0 * 256 + c0);
  uint4 wk1 = *(const uint4*)(Wlh + 1 * 256 + c0);
  uint4 wk2 = *(const uint4*)(Wlh + 2 * 256 + c0);
  uint4 wk3 = *(const uint4*)(Wlh + 3 * 256 + c0);

  int beg   = __builtin_amdgcn_readfirstlane(off2[n]);
  int pairs = __builtin_amdgcn_readfirstlane((off2[n + 1] - beg) >> 1);

  float den = 0.f, ac0=0.f, ac1=0.f, ac2=0.f, ac3=0.f;

  // scalar prefetch of pair 0
  int   sA = __builtin_amdgcn_readfirstlane(ssrc[beg]);
  int   sB = __builtin_amdgcn_readfirstlane(ssrc[beg + 1]);
  float eA = sea[beg], eB = sea[beg + 1];
  uint4 xA = xh16[max(sA, 0)];
  uint4 xB = xh16[max(sB, 0)];

  for (int p = 0; p < pairs; ++p) {
    int   csA = sA, csB = sB;
    float ceA = eA, ceB = eB;
    uint4 cxA = xA, cxB = xB;
    if (p + 1 < pairs) {
      int j = beg + 2 * (p + 1);
      sA = __builtin_amdgcn_readfirstlane(ssrc[j]);
      sB = __builtin_amdgcn_readfirstlane(ssrc[j + 1]);
      eA = sea[j];  eB = sea[j + 1];
      xA = xh16[max(sA, 0)];
      xB = xh16[max(sB, 0)];
    }
    float vA0 = dot8h(cxA, wk0.x, wk1.x, wk2.x, wk3.x);
    float vA1 = dot8h(cxA, wk0.y, wk1.y, wk2.y, wk3.y);
    float vA2 = dot8h(cxA, wk0.z, wk1.z, wk2.z, wk3.z);
    float vA3 = dot8h(cxA, wk0.w, wk1.w, wk2.w, wk3.w);
    float vB0 = dot8h(cxB, wk0.x, wk1.x, wk2.x, wk3.x);
    float vB1 = dot8h(cxB, wk0.y, wk1.y, wk2.y, wk3.y);
    float vB2 = dot8h(cxB, wk0.z, wk1.z, wk2.z, wk3.z);
    float vB3 = dot8h(cxB, wk0.w, wk1.w, wk2.w, wk3.w);

    float mA0 = vA0 + fmaf(ceA, wev.x, xr0); mA0 = fmaxf(mA0, 0.2f*mA0);
    float mA1 = vA1 + fmaf(ceA, wev.y, xr1); mA1 = fmaxf(mA1, 0.2f*mA1);
    float mA2 = vA2 + fmaf(ceA, wev.z, xr2); mA2 = fmaxf(mA2, 0.2f*mA2);
    float mA3 = vA3 + fmaf(ceA, wev.w, xr3); mA3 = fmaxf(mA3, 0.2f*mA3);
    float mB0 = vB0 + fmaf(ceB, wev.x, xr0); mB0 = fmaxf(mB0, 0.2f*mB0);
    float mB1 = vB1 + fmaf(ceB, wev.y, xr1); mB1 = fmaxf(mB1, 0.2f*mB1);
    float mB2 = vB2 + fmaf(ceB, wev.z, xr2); mB2 = fmaxf(mB2, 0.2f*mB2);
    float mB3 = vB3 + fmaf(ceB, wev.w, xr3); mB3 = fmaxf(mB3, 0.2f*mB3);

    float pA = mA0*atv.x + mA1*atv.y + mA2*atv.z + mA3*atv.w;
    float pB = mB0*atv.x + mB1*atv.y + mB2*atv.z + mB3*atv.w;
    pA = red16d(pA);
    pB = red16d(pB);

    float wA = (csA >= 0) ? __expf(pA) : 0.f;
    float wB = (csB >= 0) ? __expf(pB) : 0.f;
    den += wA + wB;
    ac0 = fmaf(wA, vA0, fmaf(wB, vB0, ac0));
    ac1 = fmaf(wA, vA1, fmaf(wB, vB1, ac1));
    ac2 = fmaf(wA, vA2, fmaf(wB, vB2, ac2));
    ac3 = fmaf(wA, vA3, fmaf(wB, vB3, ac3));
  }

  float inv = 1.0f / (den + 1e-16f);
  float4 bv = *(const float4*)(b1 + c0);
  float o0 = ac0*inv + bv.x, o1 = ac1*inv + bv.y;
  float o2 = ac2*inv + bv.z, o3 = ac3*inv + bv.w;
  float mu = red64(o0 + o1 + o2 + o3) * (1.0f / 256.0f);
  float d0 = o0-mu, d1 = o1-mu, d2 = o2-mu, d3 = o3-mu;
  float rstd = rsqrtf(red64(d0*d0 + d1*d1 + d2*d2 + d3*d3) * (1.0f/256.0f) + LN_EPS);
  float4 gv  = *(const float4*)(g1 + c0);
  float4 bev = *(const float4*)(be1 + c0);
  float y0 = d0*rstd*gv.x + bev.x; y0 = y0 > 0.f ? y0 : __expf(y0) - 1.0f;
  float y1 = d1*rstd*gv.y + bev.y; y1 = y1 > 0.f ? y1 : __expf(y1) - 1.0f;
  float y2 = d2*rstd*gv.z + bev.z; y2 = y2 > 0.f ? y2 : __expf(y2) - 1.0f;
  float y3 = d3*rstd*gv.w + bev.w; y3 = y3 > 0.f ? y3 : __expf(y3) - 1.0f;
  unsigned lo = f2bf(y0) | (f2bf(y1) << 16);
  unsigned hi = f2bf(y2) | (f2bf(y3) << 16);
  *(uint2*)(h1b + (size_t)n * 128 + lane * 2) = make_uint2(lo, hi);
}

// ---------------- K7: MFMA GEMM  [xl2|xr2] = h1(bf16) @ Btp^T ----------------
__global__ __launch_bounds__(256) void k_gemm2(
    const unsigned* __restrict__ h1b, const unsigned short* __restrict__ Btp,
    unsigned short* __restrict__ xl2b, float* __restrict__ xr2) {
  __shared__ unsigned short Ash[64][264];
  __shared__ unsigned short Bsh[64][264];
  int t = threadIdx.x;
  int bm0 = blockIdx.x * 64;
  int n0  = blockIdx.y * 64;

#pragma unroll
  for (int i = 0; i < 8; ++i) {
    int idx = t + 256 * i;          // uint4 index; 2048 total
    int row = idx >> 5, c4 = idx & 31;
    int gm = bm0 + row;
    uint4 va = (gm < N_NODES) ? *(const uint4*)(h1b + (size_t)gm * 128 + c4 * 4)
                              : make_uint4(0,0,0,0);
    *(uint4*)(&Ash[row][c4 * 8]) = va;
    uint4 vb = *(const uint4*)((const unsigned*)Btp + (size_t)(n0 + row) * 128 + c4 * 4);
    *(uint4*)(&Bsh[row][c4 * 8]) = vb;
  }
  __syncthreads();

  int lane = t & 63, w = t >> 6;
  int lm = lane & 15, lk = (lane >> 4) * 8;
  f32x4 acc[4];
#pragma unroll
  for (int i = 0; i < 4; ++i) acc[i] = (f32x4){0.f,0.f,0.f,0.f};

#pragma unroll
  for (int kk = 0; kk < 8; ++kk) {
    bf16x8 a = *(const bf16x8*)(&Ash[16*w + lm][kk*32 + lk]);
#pragma unroll
    for (int tt = 0; tt < 4; ++tt) {
      bf16x8 b = *(const bf16x8*)(&Bsh[16*tt + lm][kk*32 + lk]);
      acc[tt] = __builtin_amdgcn_mfma_f32_16x16x32_bf16(a, b, acc[tt], 0, 0, 0);
    }
  }

#pragma unroll
  for (int tt = 0; tt < 4; ++tt) {
#pragma unroll
    for (int r = 0; r < 4; ++r) {
      int node = bm0 + 16*w + (lane >> 4) * 4 + r;
      if (node < N_NODES) {
        int colg = n0 + tt * 16 + lm;
        float v = acc[tt][r];
        if (colg < 128) xl2b[(size_t)node * 128 + colg] = (unsigned short)f2bf(v);
        else            xr2 [(size_t)node * 128 + (colg - 128)] = v;
      }
    }
  }
}

// ---------------- K8: fused GATv2 layer 2 + bias + LN + ELU + pooled atomics ------
// one wave per node; 16 lanes per edge (8 ch/lane), 4 edges/iter, depth-3 pipeline.
__global__ __launch_bounds__(256) void k_gat2(
    const unsigned* __restrict__ xl2b, const float* __restrict__ xr2,
    const float* __restrict__ We, const float* __restrict__ att,
    const float* __restrict__ b2, const float* __restrict__ g2,
    const float* __restrict__ be2,
    const int* __restrict__ off2, const int* __restrict__ ssrc,
    const float* __restrict__ sea,
    const int* __restrict__ batch,
    float* __restrict__ pool, float* __restrict__ cnt) {
  int tid = threadIdx.x;
  int lane = tid & 63;
  int wv = __builtin_amdgcn_readfirstlane(tid >> 6);
  int row = lane >> 4, col = lane & 15;
  int n = blockIdx.x * 4 + wv;
  int c0 = col * 8;               // 8 channels per lane
  int cu0 = col * 4;              // uint offset into bf16-packed row

  float wev[8], at[8], xr[8];
  *(float4*)(wev)     = *(const float4*)(We + c0);
  *(float4*)(wev + 4) = *(const float4*)(We + c0 + 4);
  *(float4*)(at)      = *(const float4*)(att + c0);
  *(float4*)(at + 4)  = *(const float4*)(att + c0 + 4);
  *(float4*)(xr)      = *(const float4*)(xr2 + (size_t)n * 128 + c0);
  *(float4*)(xr + 4)  = *(const float4*)(xr2 + (size_t)n * 128 + c0 + 4);

  int beg   = __builtin_amdgcn_readfirstlane(off2[n]);
  int quads = __builtin_amdgcn_readfirstlane((off2[n + 1] - beg) >> 2);  // >= 1

  float den = 0.f;
  float ac[8] = {0,0,0,0,0,0,0,0};

  // depth-3 pipeline; each row of 16 lanes owns one edge per quad
  int s0 = -1, s1 = -1, s2 = -1;
  float e0 = 0.f, e1 = 0.f, e2 = 0.f;
  uint4 u0 = make_uint4(0,0,0,0), u1 = u0, u2 = u0;
  {
    s0 = ssrc[beg + row]; e0 = sea[beg + row];
    u0 = *(const uint4*)(xl2b + (size_t)max(s0, 0) * 64 + cu0);
  }
  if (quads > 1) {
    s1 = ssrc[beg + 4 + row]; e1 = sea[beg + 4 + row];
    u1 = *(const uint4*)(xl2b + (size_t)max(s1, 0) * 64 + cu0);
  }
  if (quads > 2) {
    s2 = ssrc[beg + 8 + row]; e2 = sea[beg + 8 + row];
    u2 = *(const uint4*)(xl2b + (size_t)max(s2, 0) * 64 + cu0);
  }

  for (int q = 0; q < quads; ++q) {
    int cs = s0; float ce = e0; uint4 cu = u0;
    s0 = s1; e0 = e1; u0 = u1;           // SSA renames, no real moves
    s1 = s2; e1 = e2; u1 = u2;
    if (q + 3 < quads) {
      int j = beg + (q + 3) * 4 + row;
      s2 = ssrc[j]; e2 = sea[j];
      u2 = *(const uint4*)(xl2b + (size_t)max(s2, 0) * 64 + cu0);
    }
    float v[8];
    v[0]=bflo(cu.x); v[1]=bfhi(cu.x); v[2]=bflo(cu.y); v[3]=bfhi(cu.y);
    v[4]=bflo(cu.z); v[5]=bfhi(cu.z); v[6]=bflo(cu.w); v[7]=bfhi(cu.w);
    float p = 0.f;
#pragma unroll
    for (int j = 0; j < 8; ++j) {
      float m = v[j] + fmaf(ce, wev[j], xr[j]);
      m = fmaxf(m, 0.2f * m);
      p = fmaf(m, at[j], p);
    }
    p = red16d(p);                  // per-edge reduce over its 16-lane row
    float w = (cs >= 0) ? __expf(p) : 0.f;
    den += w;
#pragma unroll
    for (int j = 0; j < 8; ++j) ac[j] = fmaf(w, v[j], ac[j]);
  }
  // combine 4 rows
  den += __shfl_xor(den, 16); den += __shfl_xor(den, 32);
#pragma unroll
  for (int j = 0; j < 8; ++j) {
    ac[j] += __shfl_xor(ac[j], 16);
    ac[j] += __shfl_xor(ac[j], 32);
  }

  float inv = 1.0f / (den + 1e-16f);
  float o[8], y[8];
  float bv[8], gv[8], bev[8];
  *(float4*)(bv)      = *(const float4*)(b2 + c0);
  *(float4*)(bv + 4)  = *(const float4*)(b2 + c0 + 4);
  *(float4*)(gv)      = *(const float4*)(g2 + c0);
  *(float4*)(gv + 4)  = *(const float4*)(g2 + c0 + 4);
  *(float4*)(bev)     = *(const float4*)(be2 + c0);
  *(float4*)(bev + 4) = *(const float4*)(be2 + c0 + 4);
  float osum = 0.f;
#pragma unroll
  for (int j = 0; j < 8; ++j) { o[j] = ac[j] * inv + bv[j]; osum += o[j]; }
  // each channel appears in 4 rows -> divide by 512
  float mu = red64(osum) * (1.0f / 512.0f);
  float vsum = 0.f;
#pragma unroll
  for (int j = 0; j < 8; ++j) { o[j] -= mu; vsum += o[j] * o[j]; }
  float rstd = rsqrtf(red64(vsum) * (1.0f / 512.0f) + LN_EPS);
#pragma unroll
  for (int j = 0; j < 8; ++j) {
    float t2 = o[j] * rstd * gv[j] + bev[j];
    y[j] = t2 > 0.f ? t2 : __expf(t2) - 1.0f;
  }

  // block-level pool dedup (batch sorted -> usually 1 graph per block)
  __shared__ float pbuf[4][128];
  __shared__ int gbuf[4];
  if (row == 0) {
#pragma unroll
    for (int j = 0; j < 8; ++j) pbuf[wv][c0 + j] = y[j];
  }
  if (lane == 0) gbuf[wv] = batch[n];
  __syncthreads();
  if (wv == 0) {
    int r = blockIdx.x & (NREP - 1);
    int ch = lane;                       // handles ch and ch+64
    float acc0 = pbuf[0][ch], acc1 = pbuf[0][ch+64];
    int cg = gbuf[0], cn = 1;
#pragma unroll
    for (int i = 1; i < 4; ++i) {
      if (gbuf[i] == cg) { acc0 += pbuf[i][ch]; acc1 += pbuf[i][ch+64]; cn++; }
      else {
        float* pp = pool + ((size_t)(r * N_GRAPHS + cg)) * 128;
        atomicAdd(pp + ch, acc0); atomicAdd(pp + ch + 64, acc1);
        if (lane == 0) atomicAdd(&cnt[r * N_GRAPHS + cg], (float)cn);
        cg = gbuf[i]; acc0 = pbuf[i][ch]; acc1 = pbuf[i][ch+64]; cn = 1;
      }
    }
    float* pp = pool + ((size_t)(r * N_GRAPHS + cg)) * 128;
    atomicAdd(pp + ch, acc0); atomicAdd(pp + ch + 64, acc1);
    if (lane == 0) atomicAdd(&cnt[r * N_GRAPHS + cg], (float)cn);
  }
}

// ---------------- K9: reduce replicas, divide by count ----------------
__global__ void k_final(const float* __restrict__ pool, const float* __restrict__ cnt,
                        float* __restrict__ out) {
  int idx = blockIdx.x * 256 + threadIdx.x;
  if (idx >= N_GRAPHS * 128) return;
  int g = idx >> 7, c = idx & 127;
  float s = 0.f, nn = 0.f;
#pragma unroll
  for (int r = 0; r < NREP; ++r) {
    s  += pool[((size_t)(r * N_GRAPHS + g)) * 128 + c];
    nn += cnt[r * N_GRAPHS + g];
  }
  out[idx] = s / fmaxf(nn, 1.0f);
}

// ---------------- launch ----------------
extern "C" void kernel_launch(void* const* d_in, const int* in_sizes, int n_in,
                              void* d_out, int out_size, void* d_ws, size_t ws_size,
                              hipStream_t stream) {
  const float* x    = (const float*)d_in[0];
  const int*   ei   = (const int*)  d_in[1];
  const float* ea   = (const float*)d_in[2];
  const int*   batch= (const int*)  d_in[3];
  const float* Wl1  = (const float*)d_in[4];
  const float* Wr1  = (const float*)d_in[5];
  const float* We1  = (const float*)d_in[6];
  const float* att1 = (const float*)d_in[7];
  const float* b1   = (const float*)d_in[8];
  const float* g1   = (const float*)d_in[9];
  const float* be1  = (const float*)d_in[10];
  const float* Wl2  = (const float*)d_in[11];
  const float* Wr2  = (const float*)d_in[12];
  const float* We2  = (const float*)d_in[13];
  const float* att2 = (const float*)d_in[14];
  const float* b2   = (const float*)d_in[15];
  const float* g2   = (const float*)d_in[16];
  const float* be2  = (const float*)d_in[17];
  const int* srcp = ei;
  const int* dstp = ei + N_EDGES;

  const int MAXE2 = N_EDGES + 4 * N_NODES;

  char* ws = (char*)d_ws;
  size_t off = 0;
  auto alloc = [&](size_t bytes) {
    char* p = ws + off; off += (bytes + 15) & ~(size_t)15; return p;
  };
  int*            deg   = (int*)           alloc((size_t)N_NODES * 4);
  float*          easum = (float*)         alloc((size_t)N_NODES * 4);
  int*            cursor= (int*)           alloc((size_t)N_NODES * 4);
  int*            off2  = (int*)           alloc((size_t)(N_NODES + 1) * 4);
  int*            part  = (int*)           alloc((size_t)256 * 4);
  int*            base  = (int*)           alloc((size_t)257 * 4);
  int*            ssrc  = (int*)           alloc((size_t)MAXE2 * 4);
  float*          sea   = (float*)         alloc((size_t)MAXE2 * 4);
  uint4*          xh16  = (uint4*)         alloc((size_t)N_NODES * 16);
  unsigned*       Wlh   = (unsigned*)      alloc((size_t)4 * 256 * 4);
  unsigned*       h1b   = (unsigned*)      alloc((size_t)N_NODES * 128 * 4);  // bf16 256ch
  unsigned short* xl2b  = (unsigned short*)alloc((size_t)N_NODES * 128 * 2);  // bf16 128ch
  float*          xr2   = (float*)         alloc((size_t)N_NODES * 128 * 4);
  unsigned short* Btp   = (unsigned short*)alloc((size_t)256 * 256 * 2);
  float*          pool  = (float*)         alloc((size_t)NREP * N_GRAPHS * 128 * 4);
  float*          cnt   = (float*)         alloc((size_t)NREP * N_GRAPHS * 4);

  (void)hipMemsetAsync(deg, 0, (char*)off2 - (char*)deg, stream);   // deg, easum, cursor
  (void)hipMemsetAsync(pool, 0, ((char*)cnt + (((size_t)NREP*N_GRAPHS*4 + 15) & ~(size_t)15))
                           - (char*)pool, stream);

  k_hist   <<<N_EDGES / 256, 256, 0, stream>>>(dstp, ea, deg, easum);
  k_xprep  <<<(N_NODES + 255) / 256, 256, 0, stream>>>(x, xh16);
  k_wlprep <<<4, 256, 0, stream>>>(Wl1, Wlh);
  k_wprep  <<<256, 256, 0, stream>>>(Wl2, Wr2, Btp);
  k_scanA  <<<SCAN_BLKS, 256, 0, stream>>>(deg, part);
  k_scanB  <<<1, 256, 0, stream>>>(part, base);
  k_scanC  <<<SCAN_BLKS, 256, 0, stream>>>(deg, base, off2);
  k_self   <<<(N_NODES + 255) / 256, 256, 0, stream>>>(deg, easum, off2, ssrc, sea);
  k_scatter<<<N_EDGES / 256, 256, 0, stream>>>(srcp, dstp, ea, off2, cursor, ssrc, sea);
  k_gat1   <<<N_NODES / 4, 256, 0, stream>>>(x, xh16, Wlh, Wr1, We1, att1, b1, g1, be1,
                                             off2, ssrc, sea, h1b);
  dim3 g7((N_NODES + 63) / 64, 4);
  k_gemm2  <<<g7, 256, 0, stream>>>(h1b, Btp, xl2b, xr2);
  k_gat2   <<<N_NODES / 4, 256, 0, stream>>>((const unsigned*)xl2b, xr2, We2, att2,
                                             b2, g2, be2,
                                             off2, ssrc, sea, batch, pool, cnt);
  k_final  <<<(N_GRAPHS * 128) / 256, 256, 0, stream>>>(pool, cnt, (float*)d_out);
}